// Round 8
// baseline (346.885 us; speedup 1.0000x reference)
//
#include <hip/hip_runtime.h>
#include <hip/hip_bf16.h>
#include <cstdint>
#include <cstddef>

#define B_ 2
#define T_ 2048
#define C_ 1024
#define H_ 16
#define D_ 64

typedef unsigned short u16;
typedef unsigned int u32;

typedef __bf16 bf16x8 __attribute__((ext_vector_type(8)));
typedef float f32x4 __attribute__((ext_vector_type(4)));

// 0.125 (1/sqrt(64)) * log2(e): QK^T then produces log2-domain scores
#define QSCALE 0.18033688011112042f
#define DEFER_THR 11.5f

union BFQ {
    uint4 q;
    bf16x8 v;
    u16 s[8];
};

__device__ __forceinline__ float bf2f(u16 s) {
    union { u32 u; float f; } x;
    x.u = ((u32)s) << 16;
    return x.f;
}

__device__ __forceinline__ u16 f2bf(float f) {  // HW RTNE
    union { __bf16 h; u16 u; } c;
    c.h = (__bf16)f;
    return c.u;
}

__device__ __forceinline__ void gl_lds16(const u16* g, u16* l) {
    __builtin_amdgcn_global_load_lds(
        (const __attribute__((address_space(1))) u32*)g,
        (__attribute__((address_space(3))) u32*)l, 16, 0, 0);
}

// ---------------- fp32 -> bf16 conversions (fused, vectorized) ----------------
__global__ void cvt3_kernel(const float* __restrict__ i0, const float* __restrict__ i1,
                            const float* __restrict__ i2, u16* __restrict__ o0,
                            u16* __restrict__ o1, u16* __restrict__ o2, int n4) {
    const float* in = blockIdx.z == 0 ? i0 : (blockIdx.z == 1 ? i1 : i2);
    u16* out = blockIdx.z == 0 ? o0 : (blockIdx.z == 1 ? o1 : o2);
    int i = blockIdx.x * blockDim.x + threadIdx.x;
    int stride = gridDim.x * blockDim.x;
    for (; i < n4; i += stride) {
        float4 f = reinterpret_cast<const float4*>(in)[i];
        ushort4 o;
        o.x = f2bf(f.x);
        o.y = f2bf(f.y);
        o.z = f2bf(f.z);
        o.w = f2bf(f.w);
        reinterpret_cast<ushort4*>(out)[i] = o;
    }
}

__global__ void cvt4_kernel(const float* __restrict__ i0, const float* __restrict__ i1,
                            const float* __restrict__ i2, const float* __restrict__ i3,
                            u16* __restrict__ o0, u16* __restrict__ o1,
                            u16* __restrict__ o2, u16* __restrict__ o3, int n4) {
    int z = blockIdx.z;
    const float* in = z == 0 ? i0 : (z == 1 ? i1 : (z == 2 ? i2 : i3));
    u16* out = z == 0 ? o0 : (z == 1 ? o1 : (z == 2 ? o2 : o3));
    int i = blockIdx.x * blockDim.x + threadIdx.x;
    int stride = gridDim.x * blockDim.x;
    for (; i < n4; i += stride) {
        float4 f = reinterpret_cast<const float4*>(in)[i];
        ushort4 o;
        o.x = f2bf(f.x);
        o.y = f2bf(f.y);
        o.z = f2bf(f.z);
        o.w = f2bf(f.w);
        reinterpret_cast<ushort4*>(out)[i] = o;
    }
}

// ---------------- GEMM body: C[m,n] = sum_k A[m,k]*Bw[n,k] + bias[n]
// BM=128, BN=64, BK=64. 2-phase double-buffered LDS, both-sides XOR swizzle.
template <int OUT_BF16>
__device__ __forceinline__ void gemm_body(const u16* __restrict__ A,
                                          const u16* __restrict__ Bw,
                                          const float* __restrict__ bias,
                                          void* __restrict__ Cout,
                                          int M, int N, int K) {
    __shared__ u16 As[2][128 * 64];
    __shared__ u16 Bs[2][64 * 64];

    const int tid = threadIdx.x;
    const int lane = tid & 63;
    const int wave = tid >> 6;
    const int wm = wave >> 1, wn = wave & 1;
    const int g = lane >> 4, r = lane & 15;
    const int m0 = blockIdx.y * 128, n0 = blockIdx.x * 64;

    f32x4 acc[4][2] = {};

    const int lrow = lane >> 3;
    const int lcolS = ((lane & 7) ^ (lane >> 3)) * 8;
    const u16* Abase = A + (size_t)(m0 + lrow) * K + lcolS;
    const u16* Bbase = Bw + (size_t)(n0 + lrow) * K + lcolS;

#pragma unroll
    for (int c = 0; c < 4; ++c) {
        int ca = 4 * wave + c;
        gl_lds16(Abase + (size_t)(8 * ca) * K, As[0] + ca * 512);
    }
#pragma unroll
    for (int c = 0; c < 2; ++c) {
        int cb = 2 * wave + c;
        gl_lds16(Bbase + (size_t)(8 * cb) * K, Bs[0] + cb * 512);
    }
    __syncthreads();

    int cur = 0;
    for (int k0 = 0; k0 < K; k0 += 64) {
        if (k0 + 64 < K) {
#pragma unroll
            for (int c = 0; c < 4; ++c) {
                int ca = 4 * wave + c;
                gl_lds16(Abase + (size_t)(8 * ca) * K + k0 + 64, As[cur ^ 1] + ca * 512);
            }
#pragma unroll
            for (int c = 0; c < 2; ++c) {
                int cb = 2 * wave + c;
                gl_lds16(Bbase + (size_t)(8 * cb) * K + k0 + 64, Bs[cur ^ 1] + cb * 512);
            }
        }

#pragma unroll
        for (int kk = 0; kk < 2; ++kk) {
            bf16x8 af[4], bfv[2];
#pragma unroll
            for (int mt = 0; mt < 4; ++mt) {
                int row = wm * 64 + mt * 16 + r;
                BFQ u;
                u.q = *(const uint4*)(As[cur] + row * 64 + (((kk * 4 + g) ^ (r & 7)) * 8));
                af[mt] = u.v;
            }
#pragma unroll
            for (int nt = 0; nt < 2; ++nt) {
                int row = wn * 32 + nt * 16 + r;
                BFQ u;
                u.q = *(const uint4*)(Bs[cur] + row * 64 + (((kk * 4 + g) ^ (r & 7)) * 8));
                bfv[nt] = u.v;
            }
            __builtin_amdgcn_s_setprio(1);
#pragma unroll
            for (int mt = 0; mt < 4; ++mt)
#pragma unroll
                for (int nt = 0; nt < 2; ++nt)
                    acc[mt][nt] = __builtin_amdgcn_mfma_f32_16x16x32_bf16(af[mt], bfv[nt], acc[mt][nt], 0, 0, 0);
            __builtin_amdgcn_s_setprio(0);
        }
        __syncthreads();
        cur ^= 1;
    }

#pragma unroll
    for (int mt = 0; mt < 4; ++mt) {
#pragma unroll
        for (int nt = 0; nt < 2; ++nt) {
            int n = n0 + wn * 32 + nt * 16 + r;
            float bv = bias[n];
#pragma unroll
            for (int j = 0; j < 4; ++j) {
                int m = m0 + wm * 64 + mt * 16 + g * 4 + j;
                float val = acc[mt][nt][j] + bv;
                if (OUT_BF16)
                    ((u16*)Cout)[(size_t)m * N + n] = f2bf(val);
                else
                    ((float*)Cout)[(size_t)m * N + n] = val;
            }
        }
    }
}

__global__ __launch_bounds__(256, 3) void gemm3_kernel(
    const u16* __restrict__ A0, const u16* __restrict__ A1, const u16* __restrict__ A2,
    const u16* __restrict__ W0, const u16* __restrict__ W1, const u16* __restrict__ W2,
    const float* __restrict__ b0, const float* __restrict__ b1, const float* __restrict__ b2,
    u16* __restrict__ C0, u16* __restrict__ C1, u16* __restrict__ C2,
    int M, int N, int K) {
    int z = blockIdx.z;
    const u16* A = z == 0 ? A0 : (z == 1 ? A1 : A2);
    const u16* W = z == 0 ? W0 : (z == 1 ? W1 : W2);
    const float* bias = z == 0 ? b0 : (z == 1 ? b1 : b2);
    u16* C = z == 0 ? C0 : (z == 1 ? C1 : C2);
    gemm_body<1>(A, W, bias, C, M, N, K);
}

__global__ __launch_bounds__(256, 3) void gemm_f32_kernel(const u16* __restrict__ A,
                                                          const u16* __restrict__ W,
                                                          const float* __restrict__ bias,
                                                          float* __restrict__ C,
                                                          int M, int N, int K) {
    gemm_body<0>(A, W, bias, C, M, N, K);
}

// ---------------- causal flash attention: paired q-tiles, KV split across blocks ----
// grid: (16, B*H, 2). Block (i, bh, z): q-tiles i (light, A) and 31-i (heavy, B),
// KV tiles kv0 = z*64, z*64+128, ... 4 waves x 256 threads, each wave owns 16 q-rows
// of BOTH chains. K staged in LDS double-buffer via global_load_lds with LINEAR
// lane-order dest + pre-swizzled global source (rule #21). V reg-staged into Vt.

__device__ __forceinline__ void softmax_step(f32x4* s, int domask, int kv0, int qrow0,
                                             int g, int r, float* m_run, float* l_run,
                                             f32x4* o_acc, u16* pl) {
    float sv[4][4];
#pragma unroll
    for (int nt = 0; nt < 4; ++nt) {
#pragma unroll
        for (int j = 0; j < 4; ++j) {
            float x = s[nt][j];
            if (domask) {
                int kg = kv0 + nt * 16 + r;
                int qg = qrow0 + g * 4 + j;
                x = (kg <= qg) ? x : -1e30f;
            }
            sv[nt][j] = x;
        }
    }
    float rm[4];
#pragma unroll
    for (int j = 0; j < 4; ++j) {
        float m = fmaxf(fmaxf(sv[0][j], sv[1][j]), fmaxf(sv[2][j], sv[3][j]));
        m = fmaxf(m, __shfl_xor(m, 1));
        m = fmaxf(m, __shfl_xor(m, 2));
        m = fmaxf(m, __shfl_xor(m, 4));
        m = fmaxf(m, __shfl_xor(m, 8));
        rm[j] = m;
    }
    float grow = fmaxf(fmaxf(rm[0] - m_run[0], rm[1] - m_run[1]),
                       fmaxf(rm[2] - m_run[2], rm[3] - m_run[3]));
    float pout[4][4];
    float rs[4];
    if (__all(grow <= DEFER_THR)) {
#pragma unroll
        for (int j = 0; j < 4; ++j) {
            float mref = m_run[j];
            float p0 = __builtin_amdgcn_exp2f(sv[0][j] - mref);
            float p1 = __builtin_amdgcn_exp2f(sv[1][j] - mref);
            float p2 = __builtin_amdgcn_exp2f(sv[2][j] - mref);
            float p3 = __builtin_amdgcn_exp2f(sv[3][j] - mref);
            pout[0][j] = p0; pout[1][j] = p1; pout[2][j] = p2; pout[3][j] = p3;
            rs[j] = (p0 + p1) + (p2 + p3);
        }
    } else {
#pragma unroll
        for (int j = 0; j < 4; ++j) {
            float mnew = fmaxf(m_run[j], rm[j]);
            float fac = __builtin_amdgcn_exp2f(m_run[j] - mnew);
            float p0 = __builtin_amdgcn_exp2f(sv[0][j] - mnew);
            float p1 = __builtin_amdgcn_exp2f(sv[1][j] - mnew);
            float p2 = __builtin_amdgcn_exp2f(sv[2][j] - mnew);
            float p3 = __builtin_amdgcn_exp2f(sv[3][j] - mnew);
            pout[0][j] = p0; pout[1][j] = p1; pout[2][j] = p2; pout[3][j] = p3;
            rs[j] = (p0 + p1) + (p2 + p3);
            l_run[j] *= fac;
            m_run[j] = mnew;
#pragma unroll
            for (int nt = 0; nt < 4; ++nt) o_acc[nt][j] *= fac;
        }
    }
#pragma unroll
    for (int j = 0; j < 4; ++j) {
        float t = rs[j];
        t += __shfl_xor(t, 1);
        t += __shfl_xor(t, 2);
        t += __shfl_xor(t, 4);
        t += __shfl_xor(t, 8);
        l_run[j] += t;
        int q = g * 4 + j;
        int sw = (q & 7) << 3;
        pl[(q * 64 + 0 * 16 + r) ^ sw] = f2bf(pout[0][j]);
        pl[(q * 64 + 1 * 16 + r) ^ sw] = f2bf(pout[1][j]);
        pl[(q * 64 + 2 * 16 + r) ^ sw] = f2bf(pout[2][j]);
        pl[(q * 64 + 3 * 16 + r) ^ sw] = f2bf(pout[3][j]);
    }
}

__global__ __launch_bounds__(256, 3) void attn_kernel(const u16* __restrict__ Qp,
                                                      const u16* __restrict__ Kp,
                                                      const u16* __restrict__ Vp,
                                                      u16* __restrict__ OP0,
                                                      u16* __restrict__ OP1,
                                                      float* __restrict__ ML) {
    __shared__ u16 Kl[2][64 * 64];     // K tile double-buffer, XOR-swizzled (16KB)
    __shared__ u16 Vt[64 * 64];        // [d][kv], XOR-swizzled (8KB)
    __shared__ u16 Pl[4][2][16 * 64];  // [wave][chain: 0=B,1=A], XOR-swizzled (16KB)

    const int tid = threadIdx.x, lane = tid & 63, wave = tid >> 6;
    const int g = lane >> 4, r = lane & 15;
    const int bh = blockIdx.y, b = bh >> 4, h = bh & 15;
    const int i = blockIdx.x;
    const int z = blockIdx.z;
    const int qA0 = i * 64;           // light tile
    const int qB0 = (31 - i) * 64;    // heavy tile

    const u16* Qbh = Qp + ((size_t)b * T_) * C_ + h * 64;
    const u16* Kbh = Kp + ((size_t)b * T_) * C_ + h * 64;
    const u16* Vbh = Vp + ((size_t)b * T_) * C_ + h * 64;

    // hoist Q fragments for both chains, pre-scaled by 0.125*log2(e)
    bf16x8 aqA[2], aqB[2];
    {
        const u16* qa = Qbh + (size_t)(qA0 + wave * 16 + r) * C_ + g * 8;
        const u16* qb = Qbh + (size_t)(qB0 + wave * 16 + r) * C_ + g * 8;
        BFQ u0, u1, u2, u3;
        u0.q = *(const uint4*)(qa);
        u1.q = *(const uint4*)(qa + 32);
        u2.q = *(const uint4*)(qb);
        u3.q = *(const uint4*)(qb + 32);
#pragma unroll
        for (int e = 0; e < 8; ++e) {
            u0.s[e] = f2bf(bf2f(u0.s[e]) * QSCALE);
            u1.s[e] = f2bf(bf2f(u1.s[e]) * QSCALE);
            u2.s[e] = f2bf(bf2f(u2.s[e]) * QSCALE);
            u3.s[e] = f2bf(bf2f(u3.s[e]) * QSCALE);
        }
        aqA[0] = u0.v; aqA[1] = u1.v;
        aqB[0] = u2.v; aqB[1] = u3.v;
    }

    float mA[4], lA[4], mB[4], lB[4];
    f32x4 oA[4] = {}, oB[4] = {};
#pragma unroll
    for (int j = 0; j < 4; ++j) {
        mA[j] = -1e30f; lA[j] = 0.f;
        mB[j] = -1e30f; lB[j] = 0.f;
    }

    // K staging (rule #21): gl_lds16 writes wave-uniform base + lane*16B.
    // Call c of wave w covers contiguous elements [(w*16+c*8)*64, +512):
    // lane l lands at row w*16+c*8+(l>>3), physical chunk l&7.
    // Physical chunk p of row holds logical chunk p^(row&7); row&7 == l>>3,
    // so per-lane global source uses logical chunk (l&7)^(l>>3).
    const int klr = lane >> 3;                    // row-within-8
    const int kgcol = ((lane & 7) ^ klr) * 8;     // pre-swizzled global col

    // V staging map: kv pair vp (rows 2vp, 2vp+1), d block vd0..vd0+7
    const int vp = tid & 31;
    const int vd0 = (tid >> 5) * 8;

    // prologue: stage K[z*64] into Kl[0]; prefetch V regs
#pragma unroll
    for (int c = 0; c < 2; ++c) {
        int rb = wave * 16 + c * 8;
        gl_lds16(Kbh + (size_t)(z * 64 + rb + klr) * C_ + kgcol, Kl[0] + rb * 64);
    }
    BFQ va, vb;
    {
        const u16* vr0 = Vbh + (size_t)(z * 64 + 2 * vp) * C_ + vd0;
        va.q = *(const uint4*)(vr0);
        vb.q = *(const uint4*)(vr0 + C_);
    }
    asm volatile("s_waitcnt vmcnt(0)" ::: "memory");
    __builtin_amdgcn_s_barrier();

    int cur = 0;
    for (int kv0 = z * 64; kv0 <= qB0; kv0 += 128) {
        const int actA = (kv0 <= qA0);

        // write Vt (transposed, swizzled) from prefetched regs
#pragma unroll
        for (int ii = 0; ii < 8; ++ii) {
            int d = vd0 + ii;
            u32 pr = (u32)va.s[ii] | ((u32)vb.s[ii] << 16);
            *(u32*)&Vt[(d * 64 + 2 * vp) ^ ((d & 7) << 3)] = pr;
        }

        // K fragments from LDS (swizzled b128 reads)
        BFQ kf[2][4];
#pragma unroll
        for (int kk = 0; kk < 2; ++kk)
#pragma unroll
            for (int nt = 0; nt < 4; ++nt)
                kf[kk][nt].q = *(const uint4*)(Kl[cur] + (nt * 16 + r) * 64 + (((kk * 4 + g) ^ (r & 7)) * 8));

        // QK^T, both chains
        f32x4 sB[4] = {}, sA[4] = {};
        __builtin_amdgcn_s_setprio(1);
#pragma unroll
        for (int kk = 0; kk < 2; ++kk)
#pragma unroll
            for (int nt = 0; nt < 4; ++nt)
                sB[nt] = __builtin_amdgcn_mfma_f32_16x16x32_bf16(aqB[kk], kf[kk][nt].v, sB[nt], 0, 0, 0);
        if (actA) {
#pragma unroll
            for (int kk = 0; kk < 2; ++kk)
#pragma unroll
                for (int nt = 0; nt < 4; ++nt)
                    sA[nt] = __builtin_amdgcn_mfma_f32_16x16x32_bf16(aqA[kk], kf[kk][nt].v, sA[nt], 0, 0, 0);
        }
        __builtin_amdgcn_s_setprio(0);

        // stage next K tile into the other LDS buffer; prefetch next V regs
        if (kv0 + 128 <= qB0) {
#pragma unroll
            for (int c = 0; c < 2; ++c) {
                int rb = wave * 16 + c * 8;
                gl_lds16(Kbh + (size_t)(kv0 + 128 + rb + klr) * C_ + kgcol, Kl[cur ^ 1] + rb * 64);
            }
            const u16* vr0 = Vbh + (size_t)(kv0 + 128 + 2 * vp) * C_ + vd0;
            va.q = *(const uint4*)(vr0);
            vb.q = *(const uint4*)(vr0 + C_);
        }

        softmax_step(sB, kv0 == qB0, kv0, qB0 + wave * 16, g, r, mB, lB, oB, Pl[wave][0]);
        if (actA)
            softmax_step(sA, kv0 == qA0, kv0, qA0 + wave * 16, g, r, mA, lA, oA, Pl[wave][1]);

        asm volatile("s_waitcnt lgkmcnt(0)" ::: "memory");  // my Vt + P writes committed
        __builtin_amdgcn_s_barrier();                       // everyone's Vt visible

        // V fragments (shared by both chains)
        bf16x8 vf[2][4];
#pragma unroll
        for (int kk = 0; kk < 2; ++kk)
#pragma unroll
            for (int nt = 0; nt < 4; ++nt) {
                int d = nt * 16 + r;
                BFQ u;
                u.q = *(const uint4*)&Vt[(d * 64 + kk * 32 + g * 8) ^ ((d & 7) << 3)];
                vf[kk][nt] = u.v;
            }

        __builtin_amdgcn_s_setprio(1);
#pragma unroll
        for (int kk = 0; kk < 2; ++kk) {
            BFQ ua;
            ua.q = *(const uint4*)&Pl[wave][0][(r * 64 + kk * 32 + g * 8) ^ ((r & 7) << 3)];
#pragma unroll
            for (int nt = 0; nt < 4; ++nt)
                oB[nt] = __builtin_amdgcn_mfma_f32_16x16x32_bf16(ua.v, vf[kk][nt], oB[nt], 0, 0, 0);
        }
        if (actA) {
#pragma unroll
            for (int kk = 0; kk < 2; ++kk) {
                BFQ ua;
                ua.q = *(const uint4*)&Pl[wave][1][(r * 64 + kk * 32 + g * 8) ^ ((r & 7) << 3)];
#pragma unroll
                for (int nt = 0; nt < 4; ++nt)
                    oA[nt] = __builtin_amdgcn_mfma_f32_16x16x32_bf16(ua.v, vf[kk][nt], oA[nt], 0, 0, 0);
            }
        }
        __builtin_amdgcn_s_setprio(0);

        // my next-K staging landed; everyone done reading Vt + Kl[cur]
        asm volatile("s_waitcnt vmcnt(0)" ::: "memory");
        __builtin_amdgcn_s_barrier();
        cur ^= 1;
    }

    // epilogue: unnormalized bf16 partials + (m,l) per row
    u16* OPz = z ? OP1 : OP0;
    u16* Obh = OPz + ((size_t)b * T_) * C_ + h * 64;
    float* MLz = ML + (((size_t)z * 32 + bh) * T_) * 2;
#pragma unroll
    for (int nt = 0; nt < 4; ++nt) {
#pragma unroll
        for (int j = 0; j < 4; ++j) {
            int qgB = qB0 + wave * 16 + g * 4 + j;
            Obh[(size_t)qgB * C_ + nt * 16 + r] = f2bf(oB[nt][j]);
            int qgA = qA0 + wave * 16 + g * 4 + j;
            Obh[(size_t)qgA * C_ + nt * 16 + r] = f2bf(oA[nt][j]);
        }
    }
    if (r == 0) {
#pragma unroll
        for (int j = 0; j < 4; ++j) {
            int qgB = qB0 + wave * 16 + g * 4 + j;
            MLz[qgB * 2 + 0] = mB[j];
            MLz[qgB * 2 + 1] = lB[j];
            int qgA = qA0 + wave * 16 + g * 4 + j;
            MLz[qgA * 2 + 0] = mA[j];
            MLz[qgA * 2 + 1] = lA[j];
        }
    }
}

// ---------------- merge the two KV halves ----------------
__global__ void merge_kernel(const u16* __restrict__ O0, const u16* __restrict__ O1,
                             const float* __restrict__ ML, u16* __restrict__ Out) {
    int idx = blockIdx.x * blockDim.x + threadIdx.x;  // one per 8 elems
    size_t base = (size_t)idx * 8;
    int h = (int)((base >> 6) & 15);
    int q = (int)((base >> 10) & (T_ - 1));
    int b = (int)(base >> 21);
    int bh = b * 16 + h;
    const float* ml0 = ML + (((size_t)0 * 32 + bh) * T_ + q) * 2;
    const float* ml1 = ML + (((size_t)1 * 32 + bh) * T_ + q) * 2;
    float m0 = ml0[0], l0 = ml0[1];
    float m1 = ml1[0], l1 = ml1[1];
    float mM = fmaxf(m0, m1);
    float w0 = __builtin_amdgcn_exp2f(m0 - mM);
    float w1 = __builtin_amdgcn_exp2f(m1 - mM);
    float inv = 1.0f / (l0 * w0 + l1 * w1);
    BFQ a, c, o;
    a.q = *(const uint4*)(O0 + base);
    c.q = *(const uint4*)(O1 + base);
#pragma unroll
    for (int e = 0; e < 8; ++e)
        o.s[e] = f2bf((bf2f(a.s[e]) * w0 + bf2f(c.s[e]) * w1) * inv);
    *(uint4*)(Out + base) = o.q;
}

// ---------------- launcher ----------------
extern "C" void kernel_launch(void* const* d_in, const int* in_sizes, int n_in,
                              void* d_out, int out_size, void* d_ws, size_t ws_size,
                              hipStream_t stream) {
    const float* q = (const float*)d_in[0];
    const float* k = (const float*)d_in[1];
    const float* v = (const float*)d_in[2];
    // d_in[3] = mask (tril, known causal) - unused
    const float* Wq = (const float*)d_in[4];
    const float* bq = (const float*)d_in[5];
    const float* Wk = (const float*)d_in[6];
    const float* bk = (const float*)d_in[7];
    const float* Wv = (const float*)d_in[8];
    const float* bv = (const float*)d_in[9];
    const float* Wo = (const float*)d_in[10];
    const float* bo = (const float*)d_in[11];

    const size_t NTC = (size_t)B_ * T_ * C_;  // 4,194,304
    const size_t NW = (size_t)C_ * C_;        // 1,048,576

    char* ws = (char*)d_ws;
    size_t off = 0;
    u16* qb = (u16*)(ws + off);  off += NTC * 2;
    u16* kb = (u16*)(ws + off);  off += NTC * 2;
    u16* vb = (u16*)(ws + off);  off += NTC * 2;
    u16* Wqb = (u16*)(ws + off); off += NW * 2;
    u16* Wkb = (u16*)(ws + off); off += NW * 2;
    u16* Wvb = (u16*)(ws + off); off += NW * 2;
    u16* Wob = (u16*)(ws + off); off += NW * 2;
    u16* Qp = (u16*)(ws + off);  off += NTC * 2;
    u16* Kp = (u16*)(ws + off);  off += NTC * 2;
    u16* Vp = (u16*)(ws + off);  off += NTC * 2;
    u16* AOb = (u16*)(ws + off); off += NTC * 2;

    // after gemm3, qb/kb/vb are dead -> reuse for attention partials
    u16* OP0 = qb;            // unnormalized partial O, z=0 (bf16)
    u16* OP1 = kb;            // unnormalized partial O, z=1 (bf16)
    float* ML = (float*)vb;   // [z][bh][T][2] fp32 (m,l)

    cvt3_kernel<<<dim3(512, 1, 3), 256, 0, stream>>>(q, k, v, qb, kb, vb, (int)(NTC / 4));
    cvt4_kernel<<<dim3(128, 1, 4), 256, 0, stream>>>(Wq, Wk, Wv, Wo, Wqb, Wkb, Wvb, Wob, (int)(NW / 4));

    const int M = B_ * T_;  // 4096
    dim3 g3(C_ / 64, M / 128, 3);  // (16, 32, 3) = 1536 blocks
    gemm3_kernel<<<g3, 256, 0, stream>>>(qb, kb, vb, Wqb, Wkb, Wvb, bq, bk, bv,
                                         Qp, Kp, Vp, M, C_, C_);

    dim3 agrid(16, B_ * H_, 2);  // paired q-tiles x split-KV: 1024 blocks
    attn_kernel<<<agrid, 256, 0, stream>>>(Qp, Kp, Vp, OP0, OP1, ML);

    merge_kernel<<<(int)(NTC / 8 / 256), 256, 0, stream>>>(OP0, OP1, ML, AOb);

    dim3 g1(C_ / 64, M / 128, 1);
    gemm_f32_kernel<<<g1, 256, 0, stream>>>(AOb, Wob, bo, (float*)d_out, M, C_, C_);
}

// Round 9
// 173.988 us; speedup vs baseline: 1.9937x; 1.9937x over previous
//
#include <hip/hip_runtime.h>
#include <hip/hip_bf16.h>
#include <cstdint>
#include <cstddef>

#define B_ 2
#define T_ 2048
#define C_ 1024
#define H_ 16
#define D_ 64

typedef unsigned short u16;
typedef unsigned int u32;

typedef __bf16 bf16x8 __attribute__((ext_vector_type(8)));
typedef float f32x4 __attribute__((ext_vector_type(4)));

// 0.125 (1/sqrt(64)) * log2(e): QK^T then produces log2-domain scores
#define QSCALE 0.18033688011112042f
#define DEFER_THR 11.5f

union BFQ {
    uint4 q;
    bf16x8 v;
    u16 s[8];
};

__device__ __forceinline__ float bf2f(u16 s) {
    union { u32 u; float f; } x;
    x.u = ((u32)s) << 16;
    return x.f;
}

__device__ __forceinline__ u16 f2bf(float f) {  // HW RTNE
    union { __bf16 h; u16 u; } c;
    c.h = (__bf16)f;
    return c.u;
}

__device__ __forceinline__ void gl_lds16(const u16* g, u16* l) {
    __builtin_amdgcn_global_load_lds(
        (const __attribute__((address_space(1))) u32*)g,
        (__attribute__((address_space(3))) u32*)l, 16, 0, 0);
}

// ---------------- fp32 -> bf16 conversions (fused, vectorized) ----------------
__global__ void cvt3_kernel(const float* __restrict__ i0, const float* __restrict__ i1,
                            const float* __restrict__ i2, u16* __restrict__ o0,
                            u16* __restrict__ o1, u16* __restrict__ o2, int n4) {
    const float* in = blockIdx.z == 0 ? i0 : (blockIdx.z == 1 ? i1 : i2);
    u16* out = blockIdx.z == 0 ? o0 : (blockIdx.z == 1 ? o1 : o2);
    int i = blockIdx.x * blockDim.x + threadIdx.x;
    int stride = gridDim.x * blockDim.x;
    for (; i < n4; i += stride) {
        float4 f = reinterpret_cast<const float4*>(in)[i];
        ushort4 o;
        o.x = f2bf(f.x);
        o.y = f2bf(f.y);
        o.z = f2bf(f.z);
        o.w = f2bf(f.w);
        reinterpret_cast<ushort4*>(out)[i] = o;
    }
}

__global__ void cvt4_kernel(const float* __restrict__ i0, const float* __restrict__ i1,
                            const float* __restrict__ i2, const float* __restrict__ i3,
                            u16* __restrict__ o0, u16* __restrict__ o1,
                            u16* __restrict__ o2, u16* __restrict__ o3, int n4) {
    int z = blockIdx.z;
    const float* in = z == 0 ? i0 : (z == 1 ? i1 : (z == 2 ? i2 : i3));
    u16* out = z == 0 ? o0 : (z == 1 ? o1 : (z == 2 ? o2 : o3));
    int i = blockIdx.x * blockDim.x + threadIdx.x;
    int stride = gridDim.x * blockDim.x;
    for (; i < n4; i += stride) {
        float4 f = reinterpret_cast<const float4*>(in)[i];
        ushort4 o;
        o.x = f2bf(f.x);
        o.y = f2bf(f.y);
        o.z = f2bf(f.z);
        o.w = f2bf(f.w);
        reinterpret_cast<ushort4*>(out)[i] = o;
    }
}

// ---------------- GEMM body (m97 128x128 tile): C[m,n] = sum_k A[m,k]*Bw[n,k] + bias[n]
// BM=128, BN=128, BK=64. 2-phase double-buffered LDS, both-sides XOR swizzle.
// 4 waves as 2x2; each wave owns a 64x64 output quadrant (acc[4][4]).
template <int OUT_BF16>
__device__ __forceinline__ void gemm_body(const u16* __restrict__ A,
                                          const u16* __restrict__ Bw,
                                          const float* __restrict__ bias,
                                          void* __restrict__ Cout,
                                          int M, int N, int K) {
    __shared__ u16 As[2][128 * 64];
    __shared__ u16 Bs[2][128 * 64];

    const int tid = threadIdx.x;
    const int lane = tid & 63;
    const int wave = tid >> 6;
    const int wm = wave >> 1, wn = wave & 1;
    const int g = lane >> 4, r = lane & 15;
    const int m0 = blockIdx.y * 128, n0 = blockIdx.x * 128;

    f32x4 acc[4][4] = {};

    const int lrow = lane >> 3;
    const int lcolS = ((lane & 7) ^ (lane >> 3)) * 8;
    const u16* Abase = A + (size_t)(m0 + lrow) * K + lcolS;
    const u16* Bbase = Bw + (size_t)(n0 + lrow) * K + lcolS;

#pragma unroll
    for (int c = 0; c < 4; ++c) {
        int ch = 4 * wave + c;
        gl_lds16(Abase + (size_t)(8 * ch) * K, As[0] + ch * 512);
        gl_lds16(Bbase + (size_t)(8 * ch) * K, Bs[0] + ch * 512);
    }
    __syncthreads();

    int cur = 0;
    for (int k0 = 0; k0 < K; k0 += 64) {
        if (k0 + 64 < K) {
#pragma unroll
            for (int c = 0; c < 4; ++c) {
                int ch = 4 * wave + c;
                gl_lds16(Abase + (size_t)(8 * ch) * K + k0 + 64, As[cur ^ 1] + ch * 512);
                gl_lds16(Bbase + (size_t)(8 * ch) * K + k0 + 64, Bs[cur ^ 1] + ch * 512);
            }
        }

#pragma unroll
        for (int kk = 0; kk < 2; ++kk) {
            bf16x8 af[4], bfv[4];
#pragma unroll
            for (int mt = 0; mt < 4; ++mt) {
                int row = wm * 64 + mt * 16 + r;
                BFQ u;
                u.q = *(const uint4*)(As[cur] + row * 64 + (((kk * 4 + g) ^ (r & 7)) * 8));
                af[mt] = u.v;
            }
#pragma unroll
            for (int nt = 0; nt < 4; ++nt) {
                int row = wn * 64 + nt * 16 + r;
                BFQ u;
                u.q = *(const uint4*)(Bs[cur] + row * 64 + (((kk * 4 + g) ^ (r & 7)) * 8));
                bfv[nt] = u.v;
            }
            __builtin_amdgcn_s_setprio(1);
#pragma unroll
            for (int mt = 0; mt < 4; ++mt)
#pragma unroll
                for (int nt = 0; nt < 4; ++nt)
                    acc[mt][nt] = __builtin_amdgcn_mfma_f32_16x16x32_bf16(af[mt], bfv[nt], acc[mt][nt], 0, 0, 0);
            __builtin_amdgcn_s_setprio(0);
        }
        __syncthreads();
        cur ^= 1;
    }

#pragma unroll
    for (int mt = 0; mt < 4; ++mt) {
#pragma unroll
        for (int nt = 0; nt < 4; ++nt) {
            int n = n0 + wn * 64 + nt * 16 + r;
            float bv = bias[n];
#pragma unroll
            for (int j = 0; j < 4; ++j) {
                int m = m0 + wm * 64 + mt * 16 + g * 4 + j;
                float val = acc[mt][nt][j] + bv;
                if (OUT_BF16)
                    ((u16*)Cout)[(size_t)m * N + n] = f2bf(val);
                else
                    ((float*)Cout)[(size_t)m * N + n] = val;
            }
        }
    }
}

__global__ __launch_bounds__(256, 2) void gemm3_kernel(
    const u16* __restrict__ A0, const u16* __restrict__ A1, const u16* __restrict__ A2,
    const u16* __restrict__ W0, const u16* __restrict__ W1, const u16* __restrict__ W2,
    const float* __restrict__ b0, const float* __restrict__ b1, const float* __restrict__ b2,
    u16* __restrict__ C0, u16* __restrict__ C1, u16* __restrict__ C2,
    int M, int N, int K) {
    int z = blockIdx.z;
    const u16* A = z == 0 ? A0 : (z == 1 ? A1 : A2);
    const u16* W = z == 0 ? W0 : (z == 1 ? W1 : W2);
    const float* bias = z == 0 ? b0 : (z == 1 ? b1 : b2);
    u16* C = z == 0 ? C0 : (z == 1 ? C1 : C2);
    gemm_body<1>(A, W, bias, C, M, N, K);
}

__global__ __launch_bounds__(256, 2) void gemm_f32_kernel(const u16* __restrict__ A,
                                                          const u16* __restrict__ W,
                                                          const float* __restrict__ bias,
                                                          float* __restrict__ C,
                                                          int M, int N, int K) {
    gemm_body<0>(A, W, bias, C, M, N, K);
}

// ---------------- causal flash attention: paired q-tiles, KV split across blocks ----
// (exact R6-benched structure: reg-prefetched K frags, (256,2), z-split + merge)

__device__ __forceinline__ void softmax_step(f32x4* s, int domask, int kv0, int qrow0,
                                             int g, int r, float* m_run, float* l_run,
                                             f32x4* o_acc, u16* pl) {
    float sv[4][4];
#pragma unroll
    for (int nt = 0; nt < 4; ++nt) {
#pragma unroll
        for (int j = 0; j < 4; ++j) {
            float x = s[nt][j];
            if (domask) {
                int kg = kv0 + nt * 16 + r;
                int qg = qrow0 + g * 4 + j;
                x = (kg <= qg) ? x : -1e30f;
            }
            sv[nt][j] = x;
        }
    }
    float rm[4];
#pragma unroll
    for (int j = 0; j < 4; ++j) {
        float m = fmaxf(fmaxf(sv[0][j], sv[1][j]), fmaxf(sv[2][j], sv[3][j]));
        m = fmaxf(m, __shfl_xor(m, 1));
        m = fmaxf(m, __shfl_xor(m, 2));
        m = fmaxf(m, __shfl_xor(m, 4));
        m = fmaxf(m, __shfl_xor(m, 8));
        rm[j] = m;
    }
    float grow = fmaxf(fmaxf(rm[0] - m_run[0], rm[1] - m_run[1]),
                       fmaxf(rm[2] - m_run[2], rm[3] - m_run[3]));
    float pout[4][4];
    float rs[4];
    if (__all(grow <= DEFER_THR)) {
#pragma unroll
        for (int j = 0; j < 4; ++j) {
            float mref = m_run[j];
            float p0 = __builtin_amdgcn_exp2f(sv[0][j] - mref);
            float p1 = __builtin_amdgcn_exp2f(sv[1][j] - mref);
            float p2 = __builtin_amdgcn_exp2f(sv[2][j] - mref);
            float p3 = __builtin_amdgcn_exp2f(sv[3][j] - mref);
            pout[0][j] = p0; pout[1][j] = p1; pout[2][j] = p2; pout[3][j] = p3;
            rs[j] = (p0 + p1) + (p2 + p3);
        }
    } else {
#pragma unroll
        for (int j = 0; j < 4; ++j) {
            float mnew = fmaxf(m_run[j], rm[j]);
            float fac = __builtin_amdgcn_exp2f(m_run[j] - mnew);
            float p0 = __builtin_amdgcn_exp2f(sv[0][j] - mnew);
            float p1 = __builtin_amdgcn_exp2f(sv[1][j] - mnew);
            float p2 = __builtin_amdgcn_exp2f(sv[2][j] - mnew);
            float p3 = __builtin_amdgcn_exp2f(sv[3][j] - mnew);
            pout[0][j] = p0; pout[1][j] = p1; pout[2][j] = p2; pout[3][j] = p3;
            rs[j] = (p0 + p1) + (p2 + p3);
            l_run[j] *= fac;
            m_run[j] = mnew;
#pragma unroll
            for (int nt = 0; nt < 4; ++nt) o_acc[nt][j] *= fac;
        }
    }
#pragma unroll
    for (int j = 0; j < 4; ++j) {
        float t = rs[j];
        t += __shfl_xor(t, 1);
        t += __shfl_xor(t, 2);
        t += __shfl_xor(t, 4);
        t += __shfl_xor(t, 8);
        l_run[j] += t;
        int q = g * 4 + j;
        int sw = (q & 7) << 3;
        pl[(q * 64 + 0 * 16 + r) ^ sw] = f2bf(pout[0][j]);
        pl[(q * 64 + 1 * 16 + r) ^ sw] = f2bf(pout[1][j]);
        pl[(q * 64 + 2 * 16 + r) ^ sw] = f2bf(pout[2][j]);
        pl[(q * 64 + 3 * 16 + r) ^ sw] = f2bf(pout[3][j]);
    }
}

__global__ __launch_bounds__(256, 2) void attn_kernel(const u16* __restrict__ Qp,
                                                      const u16* __restrict__ Kp,
                                                      const u16* __restrict__ Vp,
                                                      u16* __restrict__ OP0,
                                                      u16* __restrict__ OP1,
                                                      float* __restrict__ ML) {
    __shared__ u16 Vt[64 * 64];        // [d][kv], XOR-swizzled
    __shared__ u16 Pl[4][2][16 * 64];  // [wave][chain: 0=B,1=A], XOR-swizzled

    const int tid = threadIdx.x, lane = tid & 63, wave = tid >> 6;
    const int g = lane >> 4, r = lane & 15;
    const int bh = blockIdx.y, b = bh >> 4, h = bh & 15;
    const int i = blockIdx.x;
    const int z = blockIdx.z;
    const int qA0 = i * 64;           // light tile
    const int qB0 = (31 - i) * 64;    // heavy tile

    const u16* Qbh = Qp + ((size_t)b * T_) * C_ + h * 64;
    const u16* Kbh = Kp + ((size_t)b * T_) * C_ + h * 64;
    const u16* Vbh = Vp + ((size_t)b * T_) * C_ + h * 64;

    // hoist Q fragments for both chains, pre-scaled by 0.125*log2(e)
    bf16x8 aqA[2], aqB[2];
    {
        const u16* qa = Qbh + (size_t)(qA0 + wave * 16 + r) * C_ + g * 8;
        const u16* qb = Qbh + (size_t)(qB0 + wave * 16 + r) * C_ + g * 8;
        BFQ u0, u1, u2, u3;
        u0.q = *(const uint4*)(qa);
        u1.q = *(const uint4*)(qa + 32);
        u2.q = *(const uint4*)(qb);
        u3.q = *(const uint4*)(qb + 32);
#pragma unroll
        for (int e = 0; e < 8; ++e) {
            u0.s[e] = f2bf(bf2f(u0.s[e]) * QSCALE);
            u1.s[e] = f2bf(bf2f(u1.s[e]) * QSCALE);
            u2.s[e] = f2bf(bf2f(u2.s[e]) * QSCALE);
            u3.s[e] = f2bf(bf2f(u3.s[e]) * QSCALE);
        }
        aqA[0] = u0.v; aqA[1] = u1.v;
        aqB[0] = u2.v; aqB[1] = u3.v;
    }

    float mA[4], lA[4], mB[4], lB[4];
    f32x4 oA[4] = {}, oB[4] = {};
#pragma unroll
    for (int j = 0; j < 4; ++j) {
        mA[j] = -1e30f; lA[j] = 0.f;
        mB[j] = -1e30f; lB[j] = 0.f;
    }

    // V staging map: kv pair vp (rows 2vp, 2vp+1), d block vd0..vd0+7
    const int vp = tid & 31;
    const int vd0 = (tid >> 5) * 8;

    // prologue prefetch: first tile kv0 = z*64 (always <= qB0 since qB0 >= 1024)
    BFQ kf[2][4];
#pragma unroll
    for (int kk = 0; kk < 2; ++kk)
#pragma unroll
        for (int nt = 0; nt < 4; ++nt)
            kf[kk][nt].q = *(const uint4*)(Kbh + (size_t)(z * 64 + nt * 16 + r) * C_ + kk * 32 + g * 8);
    BFQ va, vb;
    {
        const u16* vr0 = Vbh + (size_t)(z * 64 + 2 * vp) * C_ + vd0;
        va.q = *(const uint4*)(vr0);
        vb.q = *(const uint4*)(vr0 + C_);
    }

    for (int kv0 = z * 64; kv0 <= qB0; kv0 += 128) {
        const int actA = (kv0 <= qA0);

        __builtin_amdgcn_s_barrier();  // prev iter's Vt reads complete

        // write Vt (transposed, swizzled) from prefetched regs
#pragma unroll
        for (int ii = 0; ii < 8; ++ii) {
            int d = vd0 + ii;
            u32 pr = (u32)va.s[ii] | ((u32)vb.s[ii] << 16);
            *(u32*)&Vt[(d * 64 + 2 * vp) ^ ((d & 7) << 3)] = pr;
        }

        // QK^T, both chains, shared K fragments
        f32x4 sB[4] = {}, sA[4] = {};
        __builtin_amdgcn_s_setprio(1);
#pragma unroll
        for (int kk = 0; kk < 2; ++kk)
#pragma unroll
            for (int nt = 0; nt < 4; ++nt)
                sB[nt] = __builtin_amdgcn_mfma_f32_16x16x32_bf16(aqB[kk], kf[kk][nt].v, sB[nt], 0, 0, 0);
        if (actA) {
#pragma unroll
            for (int kk = 0; kk < 2; ++kk)
#pragma unroll
                for (int nt = 0; nt < 4; ++nt)
                    sA[nt] = __builtin_amdgcn_mfma_f32_16x16x32_bf16(aqA[kk], kf[kk][nt].v, sA[nt], 0, 0, 0);
        }
        __builtin_amdgcn_s_setprio(0);

        // prefetch this block's next KV tile (kv0 + 128); flies under softmax + PV
        if (kv0 + 128 <= qB0) {
            const u16* kn = Kbh + (size_t)(kv0 + 128) * C_;
#pragma unroll
            for (int kk = 0; kk < 2; ++kk)
#pragma unroll
                for (int nt = 0; nt < 4; ++nt)
                    kf[kk][nt].q = *(const uint4*)(kn + (size_t)(nt * 16 + r) * C_ + kk * 32 + g * 8);
            const u16* vr0 = Vbh + (size_t)(kv0 + 128 + 2 * vp) * C_ + vd0;
            va.q = *(const uint4*)(vr0);
            vb.q = *(const uint4*)(vr0 + C_);
        }

        softmax_step(sB, kv0 == qB0, kv0, qB0 + wave * 16, g, r, mB, lB, oB, Pl[wave][0]);
        if (actA)
            softmax_step(sA, kv0 == qA0, kv0, qA0 + wave * 16, g, r, mA, lA, oA, Pl[wave][1]);

        asm volatile("s_waitcnt lgkmcnt(0)" ::: "memory");  // my Vt + P writes committed
        __builtin_amdgcn_s_barrier();                       // everyone's Vt visible

        // V fragments (shared by both chains)
        bf16x8 vf[2][4];
#pragma unroll
        for (int kk = 0; kk < 2; ++kk)
#pragma unroll
            for (int nt = 0; nt < 4; ++nt) {
                int d = nt * 16 + r;
                BFQ u;
                u.q = *(const uint4*)&Vt[(d * 64 + kk * 32 + g * 8) ^ ((d & 7) << 3)];
                vf[kk][nt] = u.v;
            }

        __builtin_amdgcn_s_setprio(1);
#pragma unroll
        for (int kk = 0; kk < 2; ++kk) {
            BFQ ua;
            ua.q = *(const uint4*)&Pl[wave][0][(r * 64 + kk * 32 + g * 8) ^ ((r & 7) << 3)];
#pragma unroll
            for (int nt = 0; nt < 4; ++nt)
                oB[nt] = __builtin_amdgcn_mfma_f32_16x16x32_bf16(ua.v, vf[kk][nt], oB[nt], 0, 0, 0);
        }
        if (actA) {
#pragma unroll
            for (int kk = 0; kk < 2; ++kk) {
                BFQ ua;
                ua.q = *(const uint4*)&Pl[wave][1][(r * 64 + kk * 32 + g * 8) ^ ((r & 7) << 3)];
#pragma unroll
                for (int nt = 0; nt < 4; ++nt)
                    oA[nt] = __builtin_amdgcn_mfma_f32_16x16x32_bf16(ua.v, vf[kk][nt], oA[nt], 0, 0, 0);
            }
        }
        __builtin_amdgcn_s_setprio(0);
    }

    // epilogue: unnormalized bf16 partials + (m,l) per row
    u16* OPz = z ? OP1 : OP0;
    u16* Obh = OPz + ((size_t)b * T_) * C_ + h * 64;
    float* MLz = ML + (((size_t)z * 32 + bh) * T_) * 2;
#pragma unroll
    for (int nt = 0; nt < 4; ++nt) {
#pragma unroll
        for (int j = 0; j < 4; ++j) {
            int qgB = qB0 + wave * 16 + g * 4 + j;
            Obh[(size_t)qgB * C_ + nt * 16 + r] = f2bf(oB[nt][j]);
            int qgA = qA0 + wave * 16 + g * 4 + j;
            Obh[(size_t)qgA * C_ + nt * 16 + r] = f2bf(oA[nt][j]);
        }
    }
    if (r == 0) {
#pragma unroll
        for (int j = 0; j < 4; ++j) {
            int qgB = qB0 + wave * 16 + g * 4 + j;
            MLz[qgB * 2 + 0] = mB[j];
            MLz[qgB * 2 + 1] = lB[j];
            int qgA = qA0 + wave * 16 + g * 4 + j;
            MLz[qgA * 2 + 0] = mA[j];
            MLz[qgA * 2 + 1] = lA[j];
        }
    }
}

// ---------------- merge the two KV halves ----------------
__global__ void merge_kernel(const u16* __restrict__ O0, const u16* __restrict__ O1,
                             const float* __restrict__ ML, u16* __restrict__ Out) {
    int idx = blockIdx.x * blockDim.x + threadIdx.x;  // one per 8 elems
    size_t base = (size_t)idx * 8;
    int h = (int)((base >> 6) & 15);
    int q = (int)((base >> 10) & (T_ - 1));
    int b = (int)(base >> 21);
    int bh = b * 16 + h;
    const float* ml0 = ML + (((size_t)0 * 32 + bh) * T_ + q) * 2;
    const float* ml1 = ML + (((size_t)1 * 32 + bh) * T_ + q) * 2;
    float m0 = ml0[0], l0 = ml0[1];
    float m1 = ml1[0], l1 = ml1[1];
    float mM = fmaxf(m0, m1);
    float w0 = __builtin_amdgcn_exp2f(m0 - mM);
    float w1 = __builtin_amdgcn_exp2f(m1 - mM);
    float inv = 1.0f / (l0 * w0 + l1 * w1);
    BFQ a, c, o;
    a.q = *(const uint4*)(O0 + base);
    c.q = *(const uint4*)(O1 + base);
#pragma unroll
    for (int e = 0; e < 8; ++e)
        o.s[e] = f2bf((bf2f(a.s[e]) * w0 + bf2f(c.s[e]) * w1) * inv);
    *(uint4*)(Out + base) = o.q;
}

// ---------------- launcher ----------------
extern "C" void kernel_launch(void* const* d_in, const int* in_sizes, int n_in,
                              void* d_out, int out_size, void* d_ws, size_t ws_size,
                              hipStream_t stream) {
    const float* q = (const float*)d_in[0];
    const float* k = (const float*)d_in[1];
    const float* v = (const float*)d_in[2];
    // d_in[3] = mask (tril, known causal) - unused
    const float* Wq = (const float*)d_in[4];
    const float* bq = (const float*)d_in[5];
    const float* Wk = (const float*)d_in[6];
    const float* bk = (const float*)d_in[7];
    const float* Wv = (const float*)d_in[8];
    const float* bv = (const float*)d_in[9];
    const float* Wo = (const float*)d_in[10];
    const float* bo = (const float*)d_in[11];

    const size_t NTC = (size_t)B_ * T_ * C_;  // 4,194,304
    const size_t NW = (size_t)C_ * C_;        // 1,048,576

    char* ws = (char*)d_ws;
    size_t off = 0;
    u16* qb = (u16*)(ws + off);  off += NTC * 2;
    u16* kb = (u16*)(ws + off);  off += NTC * 2;
    u16* vb = (u16*)(ws + off);  off += NTC * 2;
    u16* Wqb = (u16*)(ws + off); off += NW * 2;
    u16* Wkb = (u16*)(ws + off); off += NW * 2;
    u16* Wvb = (u16*)(ws + off); off += NW * 2;
    u16* Wob = (u16*)(ws + off); off += NW * 2;
    u16* Qp = (u16*)(ws + off);  off += NTC * 2;
    u16* Kp = (u16*)(ws + off);  off += NTC * 2;
    u16* Vp = (u16*)(ws + off);  off += NTC * 2;
    u16* AOb = (u16*)(ws + off); off += NTC * 2;

    // after gemm3, qb/kb/vb are dead -> reuse for attention partials
    u16* OP0 = qb;            // unnormalized partial O, z=0 (bf16)
    u16* OP1 = kb;            // unnormalized partial O, z=1 (bf16)
    float* ML = (float*)vb;   // [z][bh][T][2] fp32 (m,l)

    cvt3_kernel<<<dim3(512, 1, 3), 256, 0, stream>>>(q, k, v, qb, kb, vb, (int)(NTC / 4));
    cvt4_kernel<<<dim3(128, 1, 4), 256, 0, stream>>>(Wq, Wk, Wv, Wo, Wqb, Wkb, Wvb, Wob, (int)(NW / 4));

    const int M = B_ * T_;  // 4096
    dim3 g3(C_ / 128, M / 128, 3);  // (8, 32, 3) = 768 blocks
    gemm3_kernel<<<g3, 256, 0, stream>>>(qb, kb, vb, Wqb, Wkb, Wvb, bq, bk, bv,
                                         Qp, Kp, Vp, M, C_, C_);

    dim3 agrid(16, B_ * H_, 2);  // paired q-tiles x split-KV: 1024 blocks
    attn_kernel<<<agrid, 256, 0, stream>>>(Qp, Kp, Vp, OP0, OP1, ML);

    merge_kernel<<<(int)(NTC / 8 / 256), 256, 0, stream>>>(OP0, OP1, ML, AOb);

    dim3 g1(C_ / 128, M / 128, 1);
    gemm_f32_kernel<<<g1, 256, 0, stream>>>(AOb, Wob, bo, (float*)d_out, M, C_, C_);
}

// Round 10
// 165.714 us; speedup vs baseline: 2.0933x; 1.0499x over previous
//
#include <hip/hip_runtime.h>
#include <hip/hip_bf16.h>
#include <cstdint>
#include <cstddef>

#define B_ 2
#define T_ 2048
#define C_ 1024
#define H_ 16
#define D_ 64

typedef unsigned short u16;
typedef unsigned int u32;

typedef __bf16 bf16x8 __attribute__((ext_vector_type(8)));
typedef float f32x4 __attribute__((ext_vector_type(4)));

// 0.125 (1/sqrt(64)) * log2(e): QK^T then produces log2-domain scores
#define QSCALE 0.18033688011112042f
#define DEFER_THR 11.5f

union BFQ {
    uint4 q;
    bf16x8 v;
    u16 s[8];
};

__device__ __forceinline__ float bf2f(u16 s) {
    union { u32 u; float f; } x;
    x.u = ((u32)s) << 16;
    return x.f;
}

__device__ __forceinline__ u16 f2bf(float f) {  // HW RTNE
    union { __bf16 h; u16 u; } c;
    c.h = (__bf16)f;
    return c.u;
}

__device__ __forceinline__ void gl_lds16(const u16* g, u16* l) {
    __builtin_amdgcn_global_load_lds(
        (const __attribute__((address_space(1))) u32*)g,
        (__attribute__((address_space(3))) u32*)l, 16, 0, 0);
}

// ---------------- fp32 -> bf16 conversions (fused, vectorized) ----------------
__global__ void cvt3_kernel(const float* __restrict__ i0, const float* __restrict__ i1,
                            const float* __restrict__ i2, u16* __restrict__ o0,
                            u16* __restrict__ o1, u16* __restrict__ o2, int n4) {
    const float* in = blockIdx.z == 0 ? i0 : (blockIdx.z == 1 ? i1 : i2);
    u16* out = blockIdx.z == 0 ? o0 : (blockIdx.z == 1 ? o1 : o2);
    int i = blockIdx.x * blockDim.x + threadIdx.x;
    int stride = gridDim.x * blockDim.x;
    for (; i < n4; i += stride) {
        float4 f = reinterpret_cast<const float4*>(in)[i];
        ushort4 o;
        o.x = f2bf(f.x);
        o.y = f2bf(f.y);
        o.z = f2bf(f.z);
        o.w = f2bf(f.w);
        reinterpret_cast<ushort4*>(out)[i] = o;
    }
}

__global__ void cvt4_kernel(const float* __restrict__ i0, const float* __restrict__ i1,
                            const float* __restrict__ i2, const float* __restrict__ i3,
                            u16* __restrict__ o0, u16* __restrict__ o1,
                            u16* __restrict__ o2, u16* __restrict__ o3, int n4) {
    int z = blockIdx.z;
    const float* in = z == 0 ? i0 : (z == 1 ? i1 : (z == 2 ? i2 : i3));
    u16* out = z == 0 ? o0 : (z == 1 ? o1 : (z == 2 ? o2 : o3));
    int i = blockIdx.x * blockDim.x + threadIdx.x;
    int stride = gridDim.x * blockDim.x;
    for (; i < n4; i += stride) {
        float4 f = reinterpret_cast<const float4*>(in)[i];
        ushort4 o;
        o.x = f2bf(f.x);
        o.y = f2bf(f.y);
        o.z = f2bf(f.z);
        o.w = f2bf(f.w);
        reinterpret_cast<ushort4*>(out)[i] = o;
    }
}

// ---------------- GEMM body (R6 config): C[m,n] = sum_k A[m,k]*Bw[n,k] + bias[n]
// BM=128, BN=64, BK=64. 2-phase double-buffered LDS, both-sides XOR swizzle.
template <int OUT_BF16>
__device__ __forceinline__ void gemm_body(const u16* __restrict__ A,
                                          const u16* __restrict__ Bw,
                                          const float* __restrict__ bias,
                                          void* __restrict__ Cout,
                                          int M, int N, int K) {
    __shared__ u16 As[2][128 * 64];
    __shared__ u16 Bs[2][64 * 64];

    const int tid = threadIdx.x;
    const int lane = tid & 63;
    const int wave = tid >> 6;
    const int wm = wave >> 1, wn = wave & 1;
    const int g = lane >> 4, r = lane & 15;
    const int m0 = blockIdx.y * 128, n0 = blockIdx.x * 64;

    f32x4 acc[4][2] = {};

    const int lrow = lane >> 3;
    const int lcolS = ((lane & 7) ^ (lane >> 3)) * 8;
    const u16* Abase = A + (size_t)(m0 + lrow) * K + lcolS;
    const u16* Bbase = Bw + (size_t)(n0 + lrow) * K + lcolS;

#pragma unroll
    for (int c = 0; c < 4; ++c) {
        int ca = 4 * wave + c;
        gl_lds16(Abase + (size_t)(8 * ca) * K, As[0] + ca * 512);
    }
#pragma unroll
    for (int c = 0; c < 2; ++c) {
        int cb = 2 * wave + c;
        gl_lds16(Bbase + (size_t)(8 * cb) * K, Bs[0] + cb * 512);
    }
    __syncthreads();

    int cur = 0;
    for (int k0 = 0; k0 < K; k0 += 64) {
        if (k0 + 64 < K) {
#pragma unroll
            for (int c = 0; c < 4; ++c) {
                int ca = 4 * wave + c;
                gl_lds16(Abase + (size_t)(8 * ca) * K + k0 + 64, As[cur ^ 1] + ca * 512);
            }
#pragma unroll
            for (int c = 0; c < 2; ++c) {
                int cb = 2 * wave + c;
                gl_lds16(Bbase + (size_t)(8 * cb) * K + k0 + 64, Bs[cur ^ 1] + cb * 512);
            }
        }

#pragma unroll
        for (int kk = 0; kk < 2; ++kk) {
            bf16x8 af[4], bfv[2];
#pragma unroll
            for (int mt = 0; mt < 4; ++mt) {
                int row = wm * 64 + mt * 16 + r;
                BFQ u;
                u.q = *(const uint4*)(As[cur] + row * 64 + (((kk * 4 + g) ^ (r & 7)) * 8));
                af[mt] = u.v;
            }
#pragma unroll
            for (int nt = 0; nt < 2; ++nt) {
                int row = wn * 32 + nt * 16 + r;
                BFQ u;
                u.q = *(const uint4*)(Bs[cur] + row * 64 + (((kk * 4 + g) ^ (r & 7)) * 8));
                bfv[nt] = u.v;
            }
            __builtin_amdgcn_s_setprio(1);
#pragma unroll
            for (int mt = 0; mt < 4; ++mt)
#pragma unroll
                for (int nt = 0; nt < 2; ++nt)
                    acc[mt][nt] = __builtin_amdgcn_mfma_f32_16x16x32_bf16(af[mt], bfv[nt], acc[mt][nt], 0, 0, 0);
            __builtin_amdgcn_s_setprio(0);
        }
        __syncthreads();
        cur ^= 1;
    }

#pragma unroll
    for (int mt = 0; mt < 4; ++mt) {
#pragma unroll
        for (int nt = 0; nt < 2; ++nt) {
            int n = n0 + wn * 32 + nt * 16 + r;
            float bv = bias[n];
#pragma unroll
            for (int j = 0; j < 4; ++j) {
                int m = m0 + wm * 64 + mt * 16 + g * 4 + j;
                float val = acc[mt][nt][j] + bv;
                if (OUT_BF16)
                    ((u16*)Cout)[(size_t)m * N + n] = f2bf(val);
                else
                    ((float*)Cout)[(size_t)m * N + n] = val;
            }
        }
    }
}

__global__ __launch_bounds__(256, 3) void gemm3_kernel(
    const u16* __restrict__ A0, const u16* __restrict__ A1, const u16* __restrict__ A2,
    const u16* __restrict__ W0, const u16* __restrict__ W1, const u16* __restrict__ W2,
    const float* __restrict__ b0, const float* __restrict__ b1, const float* __restrict__ b2,
    u16* __restrict__ C0, u16* __restrict__ C1, u16* __restrict__ C2,
    int M, int N, int K) {
    int z = blockIdx.z;
    const u16* A = z == 0 ? A0 : (z == 1 ? A1 : A2);
    const u16* W = z == 0 ? W0 : (z == 1 ? W1 : W2);
    const float* bias = z == 0 ? b0 : (z == 1 ? b1 : b2);
    u16* C = z == 0 ? C0 : (z == 1 ? C1 : C2);
    gemm_body<1>(A, W, bias, C, M, N, K);
}

__global__ __launch_bounds__(256, 3) void gemm_f32_kernel(const u16* __restrict__ A,
                                                          const u16* __restrict__ W,
                                                          const float* __restrict__ bias,
                                                          float* __restrict__ C,
                                                          int M, int N, int K) {
    gemm_body<0>(A, W, bias, C, M, N, K);
}

// ---------------- causal flash attention: paired q-tiles + split-KV + swapped QK^T --
// grid (16, B*H, 2). Swapped MFMA: S^T = mfma(K, Q) -> lane (g,r) holds
// S^T[kv=nt*16+g*4+j][q=r]; softmax row-reduce is lane-local tree + 2 shuffles.
// m/l are per-lane scalars (q=r). P packed via 4x ds_write_b64 into swizzled Pl;
// PV reads Pl as A-frag (unchanged).

__device__ __forceinline__ void softmax_swapped(f32x4* s, int domask, int kv0, int qcol0,
                                                int g, int r, float& m_run, float& l_run,
                                                f32x4* o_acc, u16* pl) {
    float sv[4][4];
#pragma unroll
    for (int nt = 0; nt < 4; ++nt) {
#pragma unroll
        for (int j = 0; j < 4; ++j) {
            float x = s[nt][j];
            if (domask) {
                int kg = kv0 + nt * 16 + g * 4 + j;
                int qg = qcol0 + r;
                x = (kg <= qg) ? x : -1e30f;
            }
            sv[nt][j] = x;
        }
    }
    // lane-local tree max over 16 values (all belong to q = qcol0 + r)
    float m0 = fmaxf(fmaxf(sv[0][0], sv[0][1]), fmaxf(sv[0][2], sv[0][3]));
    float m1 = fmaxf(fmaxf(sv[1][0], sv[1][1]), fmaxf(sv[1][2], sv[1][3]));
    float m2 = fmaxf(fmaxf(sv[2][0], sv[2][1]), fmaxf(sv[2][2], sv[2][3]));
    float m3 = fmaxf(fmaxf(sv[3][0], sv[3][1]), fmaxf(sv[3][2], sv[3][3]));
    float rm = fmaxf(fmaxf(m0, m1), fmaxf(m2, m3));
    rm = fmaxf(rm, __shfl_xor(rm, 16));
    rm = fmaxf(rm, __shfl_xor(rm, 32));

    if (!__all(rm - m_run <= DEFER_THR)) {
        float mnew = fmaxf(m_run, rm);
        float fac = __builtin_amdgcn_exp2f(m_run - mnew);
        l_run *= fac;
        m_run = mnew;
        // redistribute fac (q=r layout) to O rows (q=g*4+j layout)
#pragma unroll
        for (int j = 0; j < 4; ++j) {
            float fo = __shfl(fac, g * 4 + j);
#pragma unroll
            for (int nt = 0; nt < 4; ++nt) o_acc[nt][j] *= fo;
        }
    }

    float p[4][4];
#pragma unroll
    for (int nt = 0; nt < 4; ++nt)
#pragma unroll
        for (int j = 0; j < 4; ++j)
            p[nt][j] = __builtin_amdgcn_exp2f(sv[nt][j] - m_run);

    float s0 = (p[0][0] + p[0][1]) + (p[0][2] + p[0][3]);
    float s1 = (p[1][0] + p[1][1]) + (p[1][2] + p[1][3]);
    float s2 = (p[2][0] + p[2][1]) + (p[2][2] + p[2][3]);
    float s3 = (p[3][0] + p[3][1]) + (p[3][2] + p[3][3]);
    float rs = (s0 + s1) + (s2 + s3);
    rs += __shfl_xor(rs, 16);
    rs += __shfl_xor(rs, 32);
    l_run += rs;

    // pack & write P[q=r][kv] (A-frag layout for PV), swizzled b64 writes
    const int sw = (r & 7) << 3;
#pragma unroll
    for (int nt = 0; nt < 4; ++nt) {
        uint2 w;
        w.x = (u32)f2bf(p[nt][0]) | ((u32)f2bf(p[nt][1]) << 16);
        w.y = (u32)f2bf(p[nt][2]) | ((u32)f2bf(p[nt][3]) << 16);
        *(uint2*)&pl[(r * 64 + nt * 16 + g * 4) ^ sw] = w;
    }
}

__global__ __launch_bounds__(256, 2) void attn_kernel(const u16* __restrict__ Qp,
                                                      const u16* __restrict__ Kp,
                                                      const u16* __restrict__ Vp,
                                                      u16* __restrict__ OP0,
                                                      u16* __restrict__ OP1,
                                                      float* __restrict__ ML) {
    __shared__ u16 Vt[64 * 64];        // [d][kv], XOR-swizzled
    __shared__ u16 Pl[4][2][16 * 64];  // [wave][chain: 0=B,1=A], XOR-swizzled

    const int tid = threadIdx.x, lane = tid & 63, wave = tid >> 6;
    const int g = lane >> 4, r = lane & 15;
    const int bh = blockIdx.y, b = bh >> 4, h = bh & 15;
    const int i = blockIdx.x;
    const int z = blockIdx.z;
    const int qA0 = i * 64;           // light tile
    const int qB0 = (31 - i) * 64;    // heavy tile

    const u16* Qbh = Qp + ((size_t)b * T_) * C_ + h * 64;
    const u16* Kbh = Kp + ((size_t)b * T_) * C_ + h * 64;
    const u16* Vbh = Vp + ((size_t)b * T_) * C_ + h * 64;

    // hoist Q fragments for both chains, pre-scaled by 0.125*log2(e)
    bf16x8 aqA[2], aqB[2];
    {
        const u16* qa = Qbh + (size_t)(qA0 + wave * 16 + r) * C_ + g * 8;
        const u16* qb = Qbh + (size_t)(qB0 + wave * 16 + r) * C_ + g * 8;
        BFQ u0, u1, u2, u3;
        u0.q = *(const uint4*)(qa);
        u1.q = *(const uint4*)(qa + 32);
        u2.q = *(const uint4*)(qb);
        u3.q = *(const uint4*)(qb + 32);
#pragma unroll
        for (int e = 0; e < 8; ++e) {
            u0.s[e] = f2bf(bf2f(u0.s[e]) * QSCALE);
            u1.s[e] = f2bf(bf2f(u1.s[e]) * QSCALE);
            u2.s[e] = f2bf(bf2f(u2.s[e]) * QSCALE);
            u3.s[e] = f2bf(bf2f(u3.s[e]) * QSCALE);
        }
        aqA[0] = u0.v; aqA[1] = u1.v;
        aqB[0] = u2.v; aqB[1] = u3.v;
    }

    float mA = -1e30f, lA = 0.f, mB = -1e30f, lB = 0.f;
    f32x4 oA[4] = {}, oB[4] = {};

    // V staging map: kv pair vp (rows 2vp, 2vp+1), d block vd0..vd0+7
    const int vp = tid & 31;
    const int vd0 = (tid >> 5) * 8;

    // prologue prefetch: first tile kv0 = z*64 (always <= qB0 since qB0 >= 1024)
    BFQ kf[2][4];
#pragma unroll
    for (int kk = 0; kk < 2; ++kk)
#pragma unroll
        for (int nt = 0; nt < 4; ++nt)
            kf[kk][nt].q = *(const uint4*)(Kbh + (size_t)(z * 64 + nt * 16 + r) * C_ + kk * 32 + g * 8);
    BFQ va, vb;
    {
        const u16* vr0 = Vbh + (size_t)(z * 64 + 2 * vp) * C_ + vd0;
        va.q = *(const uint4*)(vr0);
        vb.q = *(const uint4*)(vr0 + C_);
    }

    for (int kv0 = z * 64; kv0 <= qB0; kv0 += 128) {
        const int actA = (kv0 <= qA0);

        __builtin_amdgcn_s_barrier();  // prev iter's Vt reads complete

        // write Vt (transposed, swizzled) from prefetched regs
#pragma unroll
        for (int ii = 0; ii < 8; ++ii) {
            int d = vd0 + ii;
            u32 pr = (u32)va.s[ii] | ((u32)vb.s[ii] << 16);
            *(u32*)&Vt[(d * 64 + 2 * vp) ^ ((d & 7) << 3)] = pr;
        }

        // swapped QK^T: S^T = K x Q^T, both chains, shared K fragments
        f32x4 sB[4] = {}, sA[4] = {};
        __builtin_amdgcn_s_setprio(1);
#pragma unroll
        for (int kk = 0; kk < 2; ++kk)
#pragma unroll
            for (int nt = 0; nt < 4; ++nt)
                sB[nt] = __builtin_amdgcn_mfma_f32_16x16x32_bf16(kf[kk][nt].v, aqB[kk], sB[nt], 0, 0, 0);
        if (actA) {
#pragma unroll
            for (int kk = 0; kk < 2; ++kk)
#pragma unroll
                for (int nt = 0; nt < 4; ++nt)
                    sA[nt] = __builtin_amdgcn_mfma_f32_16x16x32_bf16(kf[kk][nt].v, aqA[kk], sA[nt], 0, 0, 0);
        }
        __builtin_amdgcn_s_setprio(0);

        // prefetch this block's next KV tile (kv0 + 128); flies under softmax + PV
        if (kv0 + 128 <= qB0) {
            const u16* kn = Kbh + (size_t)(kv0 + 128) * C_;
#pragma unroll
            for (int kk = 0; kk < 2; ++kk)
#pragma unroll
                for (int nt = 0; nt < 4; ++nt)
                    kf[kk][nt].q = *(const uint4*)(kn + (size_t)(nt * 16 + r) * C_ + kk * 32 + g * 8);
            const u16* vr0 = Vbh + (size_t)(kv0 + 128 + 2 * vp) * C_ + vd0;
            va.q = *(const uint4*)(vr0);
            vb.q = *(const uint4*)(vr0 + C_);
        }

        softmax_swapped(sB, kv0 == qB0, kv0, qB0 + wave * 16, g, r, mB, lB, oB, Pl[wave][0]);
        if (actA)
            softmax_swapped(sA, kv0 == qA0, kv0, qA0 + wave * 16, g, r, mA, lA, oA, Pl[wave][1]);

        asm volatile("s_waitcnt lgkmcnt(0)" ::: "memory");  // my Vt + P writes committed
        __builtin_amdgcn_s_barrier();                       // everyone's Vt visible

        // V fragments (shared by both chains)
        bf16x8 vf[2][4];
#pragma unroll
        for (int kk = 0; kk < 2; ++kk)
#pragma unroll
            for (int nt = 0; nt < 4; ++nt) {
                int d = nt * 16 + r;
                BFQ u;
                u.q = *(const uint4*)&Vt[(d * 64 + kk * 32 + g * 8) ^ ((d & 7) << 3)];
                vf[kk][nt] = u.v;
            }

        __builtin_amdgcn_s_setprio(1);
#pragma unroll
        for (int kk = 0; kk < 2; ++kk) {
            BFQ ua;
            ua.q = *(const uint4*)&Pl[wave][0][(r * 64 + kk * 32 + g * 8) ^ ((r & 7) << 3)];
#pragma unroll
            for (int nt = 0; nt < 4; ++nt)
                oB[nt] = __builtin_amdgcn_mfma_f32_16x16x32_bf16(ua.v, vf[kk][nt], oB[nt], 0, 0, 0);
        }
        if (actA) {
#pragma unroll
            for (int kk = 0; kk < 2; ++kk) {
                BFQ ua;
                ua.q = *(const uint4*)&Pl[wave][1][(r * 64 + kk * 32 + g * 8) ^ ((r & 7) << 3)];
#pragma unroll
                for (int nt = 0; nt < 4; ++nt)
                    oA[nt] = __builtin_amdgcn_mfma_f32_16x16x32_bf16(ua.v, vf[kk][nt], oA[nt], 0, 0, 0);
            }
        }
        __builtin_amdgcn_s_setprio(0);
    }

    // epilogue: unnormalized bf16 partials + (m,l) per row (g==0 lanes hold q=r state)
    u16* OPz = z ? OP1 : OP0;
    u16* Obh = OPz + ((size_t)b * T_) * C_ + h * 64;
    float* MLz = ML + (((size_t)z * 32 + bh) * T_) * 2;
#pragma unroll
    for (int nt = 0; nt < 4; ++nt) {
#pragma unroll
        for (int j = 0; j < 4; ++j) {
            int qgB = qB0 + wave * 16 + g * 4 + j;
            Obh[(size_t)qgB * C_ + nt * 16 + r] = f2bf(oB[nt][j]);
            int qgA = qA0 + wave * 16 + g * 4 + j;
            Obh[(size_t)qgA * C_ + nt * 16 + r] = f2bf(oA[nt][j]);
        }
    }
    if (g == 0) {
        int qgB = qB0 + wave * 16 + r;
        MLz[qgB * 2 + 0] = mB;
        MLz[qgB * 2 + 1] = lB;
        int qgA = qA0 + wave * 16 + r;
        MLz[qgA * 2 + 0] = mA;
        MLz[qgA * 2 + 1] = lA;
    }
}

// ---------------- merge the two KV halves ----------------
__global__ void merge_kernel(const u16* __restrict__ O0, const u16* __restrict__ O1,
                             const float* __restrict__ ML, u16* __restrict__ Out) {
    int idx = blockIdx.x * blockDim.x + threadIdx.x;  // one per 8 elems
    size_t base = (size_t)idx * 8;
    int h = (int)((base >> 6) & 15);
    int q = (int)((base >> 10) & (T_ - 1));
    int b = (int)(base >> 21);
    int bh = b * 16 + h;
    const float* ml0 = ML + (((size_t)0 * 32 + bh) * T_ + q) * 2;
    const float* ml1 = ML + (((size_t)1 * 32 + bh) * T_ + q) * 2;
    float m0 = ml0[0], l0 = ml0[1];
    float m1 = ml1[0], l1 = ml1[1];
    float mM = fmaxf(m0, m1);
    float w0 = __builtin_amdgcn_exp2f(m0 - mM);
    float w1 = __builtin_amdgcn_exp2f(m1 - mM);
    float inv = 1.0f / (l0 * w0 + l1 * w1);
    BFQ a, c, o;
    a.q = *(const uint4*)(O0 + base);
    c.q = *(const uint4*)(O1 + base);
#pragma unroll
    for (int e = 0; e < 8; ++e)
        o.s[e] = f2bf((bf2f(a.s[e]) * w0 + bf2f(c.s[e]) * w1) * inv);
    *(uint4*)(Out + base) = o.q;
}

// ---------------- launcher ----------------
extern "C" void kernel_launch(void* const* d_in, const int* in_sizes, int n_in,
                              void* d_out, int out_size, void* d_ws, size_t ws_size,
                              hipStream_t stream) {
    const float* q = (const float*)d_in[0];
    const float* k = (const float*)d_in[1];
    const float* v = (const float*)d_in[2];
    // d_in[3] = mask (tril, known causal) - unused
    const float* Wq = (const float*)d_in[4];
    const float* bq = (const float*)d_in[5];
    const float* Wk = (const float*)d_in[6];
    const float* bk = (const float*)d_in[7];
    const float* Wv = (const float*)d_in[8];
    const float* bv = (const float*)d_in[9];
    const float* Wo = (const float*)d_in[10];
    const float* bo = (const float*)d_in[11];

    const size_t NTC = (size_t)B_ * T_ * C_;  // 4,194,304
    const size_t NW = (size_t)C_ * C_;        // 1,048,576

    char* ws = (char*)d_ws;
    size_t off = 0;
    u16* qb = (u16*)(ws + off);  off += NTC * 2;
    u16* kb = (u16*)(ws + off);  off += NTC * 2;
    u16* vb = (u16*)(ws + off);  off += NTC * 2;
    u16* Wqb = (u16*)(ws + off); off += NW * 2;
    u16* Wkb = (u16*)(ws + off); off += NW * 2;
    u16* Wvb = (u16*)(ws + off); off += NW * 2;
    u16* Wob = (u16*)(ws + off); off += NW * 2;
    u16* Qp = (u16*)(ws + off);  off += NTC * 2;
    u16* Kp = (u16*)(ws + off);  off += NTC * 2;
    u16* Vp = (u16*)(ws + off);  off += NTC * 2;
    u16* AOb = (u16*)(ws + off); off += NTC * 2;

    // after gemm3, qb/kb/vb are dead -> reuse for attention partials
    u16* OP0 = qb;            // unnormalized partial O, z=0 (bf16)
    u16* OP1 = kb;            // unnormalized partial O, z=1 (bf16)
    float* ML = (float*)vb;   // [z][bh][T][2] fp32 (m,l)

    cvt3_kernel<<<dim3(512, 1, 3), 256, 0, stream>>>(q, k, v, qb, kb, vb, (int)(NTC / 4));
    cvt4_kernel<<<dim3(128, 1, 4), 256, 0, stream>>>(Wq, Wk, Wv, Wo, Wqb, Wkb, Wvb, Wob, (int)(NW / 4));

    const int M = B_ * T_;  // 4096
    dim3 g3(C_ / 64, M / 128, 3);  // (16, 32, 3) = 1536 blocks
    gemm3_kernel<<<g3, 256, 0, stream>>>(qb, kb, vb, Wqb, Wkb, Wvb, bq, bk, bv,
                                         Qp, Kp, Vp, M, C_, C_);

    dim3 agrid(16, B_ * H_, 2);  // paired q-tiles x split-KV: 1024 blocks
    attn_kernel<<<agrid, 256, 0, stream>>>(Qp, Kp, Vp, OP0, OP1, ML);

    merge_kernel<<<(int)(NTC / 8 / 256), 256, 0, stream>>>(OP0, OP1, ML, AOb);

    dim3 g1(C_ / 64, M / 128, 1);
    gemm_f32_kernel<<<g1, 256, 0, stream>>>(AOb, Wob, bo, (float*)d_out, M, C_, C_);
}

// Round 11
// 136.121 us; speedup vs baseline: 2.5484x; 1.2174x over previous
//
#include <hip/hip_runtime.h>
#include <hip/hip_bf16.h>
#include <cstdint>
#include <cstddef>

#define B_ 2
#define T_ 2048
#define C_ 1024
#define H_ 16
#define D_ 64

typedef unsigned short u16;
typedef unsigned int u32;

typedef __bf16 bf16x8 __attribute__((ext_vector_type(8)));
typedef float f32x4 __attribute__((ext_vector_type(4)));

// 0.125 (1/sqrt(64)) * log2(e): QK^T then produces log2-domain scores
#define QSCALE 0.18033688011112042f
#define DEFER_THR 11.5f

union BFQ {
    uint4 q;
    bf16x8 v;
    u16 s[8];
};

__device__ __forceinline__ float bf2f(u16 s) {
    union { u32 u; float f; } x;
    x.u = ((u32)s) << 16;
    return x.f;
}

__device__ __forceinline__ u16 f2bf(float f) {  // HW RTNE
    union { __bf16 h; u16 u; } c;
    c.h = (__bf16)f;
    return c.u;
}

__device__ __forceinline__ void gl_lds16(const u16* g, u16* l) {
    __builtin_amdgcn_global_load_lds(
        (const __attribute__((address_space(1))) u32*)g,
        (__attribute__((address_space(3))) u32*)l, 16, 0, 0);
}

// ---------------- fp32 -> bf16 conversions (fused, vectorized) ----------------
__global__ void cvt3_kernel(const float* __restrict__ i0, const float* __restrict__ i1,
                            const float* __restrict__ i2, u16* __restrict__ o0,
                            u16* __restrict__ o1, u16* __restrict__ o2, int n4) {
    const float* in = blockIdx.z == 0 ? i0 : (blockIdx.z == 1 ? i1 : i2);
    u16* out = blockIdx.z == 0 ? o0 : (blockIdx.z == 1 ? o1 : o2);
    int i = blockIdx.x * blockDim.x + threadIdx.x;
    int stride = gridDim.x * blockDim.x;
    for (; i < n4; i += stride) {
        float4 f = reinterpret_cast<const float4*>(in)[i];
        ushort4 o;
        o.x = f2bf(f.x);
        o.y = f2bf(f.y);
        o.z = f2bf(f.z);
        o.w = f2bf(f.w);
        reinterpret_cast<ushort4*>(out)[i] = o;
    }
}

__global__ void cvt4_kernel(const float* __restrict__ i0, const float* __restrict__ i1,
                            const float* __restrict__ i2, const float* __restrict__ i3,
                            u16* __restrict__ o0, u16* __restrict__ o1,
                            u16* __restrict__ o2, u16* __restrict__ o3, int n4) {
    int z = blockIdx.z;
    const float* in = z == 0 ? i0 : (z == 1 ? i1 : (z == 2 ? i2 : i3));
    u16* out = z == 0 ? o0 : (z == 1 ? o1 : (z == 2 ? o2 : o3));
    int i = blockIdx.x * blockDim.x + threadIdx.x;
    int stride = gridDim.x * blockDim.x;
    for (; i < n4; i += stride) {
        float4 f = reinterpret_cast<const float4*>(in)[i];
        ushort4 o;
        o.x = f2bf(f.x);
        o.y = f2bf(f.y);
        o.z = f2bf(f.z);
        o.w = f2bf(f.w);
        reinterpret_cast<ushort4*>(out)[i] = o;
    }
}

// ---------------- GEMM body (R6 config): C[m,n] = sum_k A[m,k]*Bw[n,k] + bias[n]
// BM=128, BN=64, BK=64. 2-phase double-buffered LDS, both-sides XOR swizzle.
template <int OUT_BF16>
__device__ __forceinline__ void gemm_body(const u16* __restrict__ A,
                                          const u16* __restrict__ Bw,
                                          const float* __restrict__ bias,
                                          void* __restrict__ Cout,
                                          int M, int N, int K) {
    __shared__ u16 As[2][128 * 64];
    __shared__ u16 Bs[2][64 * 64];

    const int tid = threadIdx.x;
    const int lane = tid & 63;
    const int wave = tid >> 6;
    const int wm = wave >> 1, wn = wave & 1;
    const int g = lane >> 4, r = lane & 15;
    const int m0 = blockIdx.y * 128, n0 = blockIdx.x * 64;

    f32x4 acc[4][2] = {};

    const int lrow = lane >> 3;
    const int lcolS = ((lane & 7) ^ (lane >> 3)) * 8;
    const u16* Abase = A + (size_t)(m0 + lrow) * K + lcolS;
    const u16* Bbase = Bw + (size_t)(n0 + lrow) * K + lcolS;

#pragma unroll
    for (int c = 0; c < 4; ++c) {
        int ca = 4 * wave + c;
        gl_lds16(Abase + (size_t)(8 * ca) * K, As[0] + ca * 512);
    }
#pragma unroll
    for (int c = 0; c < 2; ++c) {
        int cb = 2 * wave + c;
        gl_lds16(Bbase + (size_t)(8 * cb) * K, Bs[0] + cb * 512);
    }
    __syncthreads();

    int cur = 0;
    for (int k0 = 0; k0 < K; k0 += 64) {
        if (k0 + 64 < K) {
#pragma unroll
            for (int c = 0; c < 4; ++c) {
                int ca = 4 * wave + c;
                gl_lds16(Abase + (size_t)(8 * ca) * K + k0 + 64, As[cur ^ 1] + ca * 512);
            }
#pragma unroll
            for (int c = 0; c < 2; ++c) {
                int cb = 2 * wave + c;
                gl_lds16(Bbase + (size_t)(8 * cb) * K + k0 + 64, Bs[cur ^ 1] + cb * 512);
            }
        }

#pragma unroll
        for (int kk = 0; kk < 2; ++kk) {
            bf16x8 af[4], bfv[2];
#pragma unroll
            for (int mt = 0; mt < 4; ++mt) {
                int row = wm * 64 + mt * 16 + r;
                BFQ u;
                u.q = *(const uint4*)(As[cur] + row * 64 + (((kk * 4 + g) ^ (r & 7)) * 8));
                af[mt] = u.v;
            }
#pragma unroll
            for (int nt = 0; nt < 2; ++nt) {
                int row = wn * 32 + nt * 16 + r;
                BFQ u;
                u.q = *(const uint4*)(Bs[cur] + row * 64 + (((kk * 4 + g) ^ (r & 7)) * 8));
                bfv[nt] = u.v;
            }
            __builtin_amdgcn_s_setprio(1);
#pragma unroll
            for (int mt = 0; mt < 4; ++mt)
#pragma unroll
                for (int nt = 0; nt < 2; ++nt)
                    acc[mt][nt] = __builtin_amdgcn_mfma_f32_16x16x32_bf16(af[mt], bfv[nt], acc[mt][nt], 0, 0, 0);
            __builtin_amdgcn_s_setprio(0);
        }
        __syncthreads();
        cur ^= 1;
    }

#pragma unroll
    for (int mt = 0; mt < 4; ++mt) {
#pragma unroll
        for (int nt = 0; nt < 2; ++nt) {
            int n = n0 + wn * 32 + nt * 16 + r;
            float bv = bias[n];
#pragma unroll
            for (int j = 0; j < 4; ++j) {
                int m = m0 + wm * 64 + mt * 16 + g * 4 + j;
                float val = acc[mt][nt][j] + bv;
                if (OUT_BF16)
                    ((u16*)Cout)[(size_t)m * N + n] = f2bf(val);
                else
                    ((float*)Cout)[(size_t)m * N + n] = val;
            }
        }
    }
}

__global__ __launch_bounds__(256, 3) void gemm3_kernel(
    const u16* __restrict__ A0, const u16* __restrict__ A1, const u16* __restrict__ A2,
    const u16* __restrict__ W0, const u16* __restrict__ W1, const u16* __restrict__ W2,
    const float* __restrict__ b0, const float* __restrict__ b1, const float* __restrict__ b2,
    u16* __restrict__ C0, u16* __restrict__ C1, u16* __restrict__ C2,
    int M, int N, int K) {
    int z = blockIdx.z;
    const u16* A = z == 0 ? A0 : (z == 1 ? A1 : A2);
    const u16* W = z == 0 ? W0 : (z == 1 ? W1 : W2);
    const float* bias = z == 0 ? b0 : (z == 1 ? b1 : b2);
    u16* C = z == 0 ? C0 : (z == 1 ? C1 : C2);
    gemm_body<1>(A, W, bias, C, M, N, K);
}

__global__ __launch_bounds__(256, 3) void gemm_f32_kernel(const u16* __restrict__ A,
                                                          const u16* __restrict__ W,
                                                          const float* __restrict__ bias,
                                                          float* __restrict__ C,
                                                          int M, int N, int K) {
    gemm_body<0>(A, W, bias, C, M, N, K);
}

// ---------------- causal flash attention ----------------
// 1D grid 1024, XCD-decoded: blocks sharing a head's K/V land on one XCD (T1).
// Paired q-tiles (i light, 31-i heavy) x split-KV (z even/odd 64-tiles).
// Swapped QK^T (S^T = mfma(K,Q)): lane-local softmax. K staged via
// global_load_lds double-buffer (R7-verified linear+preswizzle pattern);
// V reg-staged with full-iteration slack -> transposed swizzled Vt.

__device__ __forceinline__ void softmax_swapped(f32x4* s, int domask, int kv0, int qcol0,
                                                int g, int r, float& m_run, float& l_run,
                                                f32x4* o_acc, u16* pl) {
    float sv[4][4];
#pragma unroll
    for (int nt = 0; nt < 4; ++nt) {
#pragma unroll
        for (int j = 0; j < 4; ++j) {
            float x = s[nt][j];
            if (domask) {
                int kg = kv0 + nt * 16 + g * 4 + j;
                int qg = qcol0 + r;
                x = (kg <= qg) ? x : -1e30f;
            }
            sv[nt][j] = x;
        }
    }
    // lane-local tree max over 16 values (all belong to q = qcol0 + r)
    float m0 = fmaxf(fmaxf(sv[0][0], sv[0][1]), fmaxf(sv[0][2], sv[0][3]));
    float m1 = fmaxf(fmaxf(sv[1][0], sv[1][1]), fmaxf(sv[1][2], sv[1][3]));
    float m2 = fmaxf(fmaxf(sv[2][0], sv[2][1]), fmaxf(sv[2][2], sv[2][3]));
    float m3 = fmaxf(fmaxf(sv[3][0], sv[3][1]), fmaxf(sv[3][2], sv[3][3]));
    float rm = fmaxf(fmaxf(m0, m1), fmaxf(m2, m3));
    rm = fmaxf(rm, __shfl_xor(rm, 16));
    rm = fmaxf(rm, __shfl_xor(rm, 32));

    if (!__all(rm - m_run <= DEFER_THR)) {
        float mnew = fmaxf(m_run, rm);
        float fac = __builtin_amdgcn_exp2f(m_run - mnew);
        l_run *= fac;
        m_run = mnew;
        // redistribute fac (q=r layout) to O rows (q=g*4+j layout)
#pragma unroll
        for (int j = 0; j < 4; ++j) {
            float fo = __shfl(fac, g * 4 + j);
#pragma unroll
            for (int nt = 0; nt < 4; ++nt) o_acc[nt][j] *= fo;
        }
    }

    float p[4][4];
#pragma unroll
    for (int nt = 0; nt < 4; ++nt)
#pragma unroll
        for (int j = 0; j < 4; ++j)
            p[nt][j] = __builtin_amdgcn_exp2f(sv[nt][j] - m_run);

    float s0 = (p[0][0] + p[0][1]) + (p[0][2] + p[0][3]);
    float s1 = (p[1][0] + p[1][1]) + (p[1][2] + p[1][3]);
    float s2 = (p[2][0] + p[2][1]) + (p[2][2] + p[2][3]);
    float s3 = (p[3][0] + p[3][1]) + (p[3][2] + p[3][3]);
    float rs = (s0 + s1) + (s2 + s3);
    rs += __shfl_xor(rs, 16);
    rs += __shfl_xor(rs, 32);
    l_run += rs;

    // pack & write P[q=r][kv] (A-frag layout for PV), swizzled b64 writes
    const int sw = (r & 7) << 3;
#pragma unroll
    for (int nt = 0; nt < 4; ++nt) {
        uint2 w;
        w.x = (u32)f2bf(p[nt][0]) | ((u32)f2bf(p[nt][1]) << 16);
        w.y = (u32)f2bf(p[nt][2]) | ((u32)f2bf(p[nt][3]) << 16);
        *(uint2*)&pl[(r * 64 + nt * 16 + g * 4) ^ sw] = w;
    }
}

__global__ __launch_bounds__(256, 2) void attn_kernel(const u16* __restrict__ Qp,
                                                      const u16* __restrict__ Kp,
                                                      const u16* __restrict__ Vp,
                                                      u16* __restrict__ OP0,
                                                      u16* __restrict__ OP1,
                                                      float* __restrict__ ML) {
    __shared__ u16 Kl[2][64 * 64];     // K double-buffer, XOR-swizzled (16KB)
    __shared__ u16 Vt[64 * 64];        // [d][kv], XOR-swizzled (8KB)
    __shared__ u16 Pl[4][2][16 * 64];  // [wave][chain: 0=B,1=A], XOR-swizzled (16KB)

    const int tid = threadIdx.x, lane = tid & 63, wave = tid >> 6;
    const int g = lane >> 4, r = lane & 15;

    // XCD-aware decode: 1024 blocks; xcd = id&7 gets 4 whole heads (bh) worth
    // of blocks -> per-XCD L2 holds those heads' K/V (2MB < 4MB).
    const int lid = blockIdx.x;
    const int xcd = lid & 7;
    const int idx = lid >> 3;           // 0..127
    const int bh = xcd * 4 + (idx >> 5);
    const int iz = idx & 31;
    const int i = iz & 15;
    const int z = iz >> 4;
    const int b = bh >> 4, h = bh & 15;
    const int qA0 = i * 64;             // light tile
    const int qB0 = (31 - i) * 64;      // heavy tile

    const u16* Qbh = Qp + ((size_t)b * T_) * C_ + h * 64;
    const u16* Kbh = Kp + ((size_t)b * T_) * C_ + h * 64;
    const u16* Vbh = Vp + ((size_t)b * T_) * C_ + h * 64;

    // hoist Q fragments for both chains, pre-scaled by 0.125*log2(e)
    bf16x8 aqA[2], aqB[2];
    {
        const u16* qa = Qbh + (size_t)(qA0 + wave * 16 + r) * C_ + g * 8;
        const u16* qb = Qbh + (size_t)(qB0 + wave * 16 + r) * C_ + g * 8;
        BFQ u0, u1, u2, u3;
        u0.q = *(const uint4*)(qa);
        u1.q = *(const uint4*)(qa + 32);
        u2.q = *(const uint4*)(qb);
        u3.q = *(const uint4*)(qb + 32);
#pragma unroll
        for (int e = 0; e < 8; ++e) {
            u0.s[e] = f2bf(bf2f(u0.s[e]) * QSCALE);
            u1.s[e] = f2bf(bf2f(u1.s[e]) * QSCALE);
            u2.s[e] = f2bf(bf2f(u2.s[e]) * QSCALE);
            u3.s[e] = f2bf(bf2f(u3.s[e]) * QSCALE);
        }
        aqA[0] = u0.v; aqA[1] = u1.v;
        aqB[0] = u2.v; aqB[1] = u3.v;
    }

    float mA = -1e30f, lA = 0.f, mB = -1e30f, lB = 0.f;
    f32x4 oA[4] = {}, oB[4] = {};

    // K staging (rule #21, R7-verified): wave w call c covers contiguous
    // elements [(w*16+c*8)*64, +512); lane l -> row w*16+c*8+(l>>3), phys
    // chunk l&7 which must hold logical chunk (l&7)^(l>>3).
    const int klr = lane >> 3;
    const int kgcol = ((lane & 7) ^ klr) * 8;

    // V staging map: kv pair vp (rows 2vp, 2vp+1), d block vd0..vd0+7
    const int vp = tid & 31;
    const int vd0 = (tid >> 5) * 8;

    // prologue: stage K(z*64) -> Kl[0]; load V(z*64) regs; drain; barrier
#pragma unroll
    for (int c = 0; c < 2; ++c) {
        int rb = wave * 16 + c * 8;
        gl_lds16(Kbh + (size_t)(z * 64 + rb + klr) * C_ + kgcol, Kl[0] + rb * 64);
    }
    BFQ va, vb;
    {
        const u16* vr0 = Vbh + (size_t)(z * 64 + 2 * vp) * C_ + vd0;
        va.q = *(const uint4*)(vr0);
        vb.q = *(const uint4*)(vr0 + C_);
    }
    asm volatile("s_waitcnt vmcnt(0)" ::: "memory");
    __builtin_amdgcn_s_barrier();

    int cur = 0;
    for (int kv0 = z * 64; kv0 <= qB0; kv0 += 128) {
        const int actA = (kv0 <= qA0);
        const int havenext = (kv0 + 128 <= qB0);

        __builtin_amdgcn_s_barrier();  // prev PV (Vt) reads done; Kl[cur] staged

        // write Vt (transposed, swizzled) from prefetched regs
#pragma unroll
        for (int ii = 0; ii < 8; ++ii) {
            int d = vd0 + ii;
            u32 pr = (u32)va.s[ii] | ((u32)vb.s[ii] << 16);
            *(u32*)&Vt[(d * 64 + 2 * vp) ^ ((d & 7) << 3)] = pr;
        }

        // issue next V loads now (full-iteration slack)
        if (havenext) {
            const u16* vr0 = Vbh + (size_t)(kv0 + 128 + 2 * vp) * C_ + vd0;
            va.q = *(const uint4*)(vr0);
            vb.q = *(const uint4*)(vr0 + C_);
        }

        // K fragments from LDS (swizzled b128 reads)
        BFQ kf[2][4];
#pragma unroll
        for (int kk = 0; kk < 2; ++kk)
#pragma unroll
            for (int nt = 0; nt < 4; ++nt)
                kf[kk][nt].q = *(const uint4*)(Kl[cur] + (nt * 16 + r) * 64 + (((kk * 4 + g) ^ (r & 7)) * 8));

        // swapped QK^T: S^T = K x Q^T, both chains
        f32x4 sB[4] = {}, sA[4] = {};
        __builtin_amdgcn_s_setprio(1);
#pragma unroll
        for (int kk = 0; kk < 2; ++kk)
#pragma unroll
            for (int nt = 0; nt < 4; ++nt)
                sB[nt] = __builtin_amdgcn_mfma_f32_16x16x32_bf16(kf[kk][nt].v, aqB[kk], sB[nt], 0, 0, 0);
        if (actA) {
#pragma unroll
            for (int kk = 0; kk < 2; ++kk)
#pragma unroll
                for (int nt = 0; nt < 4; ++nt)
                    sA[nt] = __builtin_amdgcn_mfma_f32_16x16x32_bf16(kf[kk][nt].v, aqA[kk], sA[nt], 0, 0, 0);
        }
        __builtin_amdgcn_s_setprio(0);

        // stage next K tile -> Kl[cur^1] (drained by end-of-iter vmcnt)
        if (havenext) {
#pragma unroll
            for (int c = 0; c < 2; ++c) {
                int rb = wave * 16 + c * 8;
                gl_lds16(Kbh + (size_t)(kv0 + 128 + rb + klr) * C_ + kgcol, Kl[cur ^ 1] + rb * 64);
            }
        }

        softmax_swapped(sB, kv0 == qB0, kv0, qB0 + wave * 16, g, r, mB, lB, oB, Pl[wave][0]);
        if (actA)
            softmax_swapped(sA, kv0 == qA0, kv0, qA0 + wave * 16, g, r, mA, lA, oA, Pl[wave][1]);

        asm volatile("s_waitcnt lgkmcnt(0)" ::: "memory");  // my Vt + P writes committed
        __builtin_amdgcn_s_barrier();                       // everyone's Vt visible

        // V fragments (shared by both chains)
        bf16x8 vf[2][4];
#pragma unroll
        for (int kk = 0; kk < 2; ++kk)
#pragma unroll
            for (int nt = 0; nt < 4; ++nt) {
                int d = nt * 16 + r;
                BFQ u;
                u.q = *(const uint4*)&Vt[(d * 64 + kk * 32 + g * 8) ^ ((d & 7) << 3)];
                vf[kk][nt] = u.v;
            }

        __builtin_amdgcn_s_setprio(1);
#pragma unroll
        for (int kk = 0; kk < 2; ++kk) {
            BFQ ua;
            ua.q = *(const uint4*)&Pl[wave][0][(r * 64 + kk * 32 + g * 8) ^ ((r & 7) << 3)];
#pragma unroll
            for (int nt = 0; nt < 4; ++nt)
                oB[nt] = __builtin_amdgcn_mfma_f32_16x16x32_bf16(ua.v, vf[kk][nt], oB[nt], 0, 0, 0);
        }
        if (actA) {
#pragma unroll
            for (int kk = 0; kk < 2; ++kk) {
                BFQ ua;
                ua.q = *(const uint4*)&Pl[wave][1][(r * 64 + kk * 32 + g * 8) ^ ((r & 7) << 3)];
#pragma unroll
                for (int nt = 0; nt < 4; ++nt)
                    oA[nt] = __builtin_amdgcn_mfma_f32_16x16x32_bf16(ua.v, vf[kk][nt], oA[nt], 0, 0, 0);
            }
        }
        __builtin_amdgcn_s_setprio(0);

        // drain my K gl_lds (and V loads) so next barrier guarantees Kl[cur^1]
        asm volatile("s_waitcnt vmcnt(0)" ::: "memory");
        cur ^= 1;
    }

    // epilogue: unnormalized bf16 partials + (m,l) per row (g==0 lanes hold q=r state)
    u16* OPz = z ? OP1 : OP0;
    u16* Obh = OPz + ((size_t)b * T_) * C_ + h * 64;
    float* MLz = ML + (((size_t)z * 32 + bh) * T_) * 2;
#pragma unroll
    for (int nt = 0; nt < 4; ++nt) {
#pragma unroll
        for (int j = 0; j < 4; ++j) {
            int qgB = qB0 + wave * 16 + g * 4 + j;
            Obh[(size_t)qgB * C_ + nt * 16 + r] = f2bf(oB[nt][j]);
            int qgA = qA0 + wave * 16 + g * 4 + j;
            Obh[(size_t)qgA * C_ + nt * 16 + r] = f2bf(oA[nt][j]);
        }
    }
    if (g == 0) {
        int qgB = qB0 + wave * 16 + r;
        MLz[qgB * 2 + 0] = mB;
        MLz[qgB * 2 + 1] = lB;
        int qgA = qA0 + wave * 16 + r;
        MLz[qgA * 2 + 0] = mA;
        MLz[qgA * 2 + 1] = lA;
    }
}

// ---------------- merge the two KV halves ----------------
__global__ void merge_kernel(const u16* __restrict__ O0, const u16* __restrict__ O1,
                             const float* __restrict__ ML, u16* __restrict__ Out) {
    int idx = blockIdx.x * blockDim.x + threadIdx.x;  // one per 8 elems
    size_t base = (size_t)idx * 8;
    int h = (int)((base >> 6) & 15);
    int q = (int)((base >> 10) & (T_ - 1));
    int b = (int)(base >> 21);
    int bh = b * 16 + h;
    const float* ml0 = ML + (((size_t)0 * 32 + bh) * T_ + q) * 2;
    const float* ml1 = ML + (((size_t)1 * 32 + bh) * T_ + q) * 2;
    float m0 = ml0[0], l0 = ml0[1];
    float m1 = ml1[0], l1 = ml1[1];
    float mM = fmaxf(m0, m1);
    float w0 = __builtin_amdgcn_exp2f(m0 - mM);
    float w1 = __builtin_amdgcn_exp2f(m1 - mM);
    float inv = 1.0f / (l0 * w0 + l1 * w1);
    BFQ a, c, o;
    a.q = *(const uint4*)(O0 + base);
    c.q = *(const uint4*)(O1 + base);
#pragma unroll
    for (int e = 0; e < 8; ++e)
        o.s[e] = f2bf((bf2f(a.s[e]) * w0 + bf2f(c.s[e]) * w1) * inv);
    *(uint4*)(Out + base) = o.q;
}

// ---------------- launcher ----------------
extern "C" void kernel_launch(void* const* d_in, const int* in_sizes, int n_in,
                              void* d_out, int out_size, void* d_ws, size_t ws_size,
                              hipStream_t stream) {
    const float* q = (const float*)d_in[0];
    const float* k = (const float*)d_in[1];
    const float* v = (const float*)d_in[2];
    // d_in[3] = mask (tril, known causal) - unused
    const float* Wq = (const float*)d_in[4];
    const float* bq = (const float*)d_in[5];
    const float* Wk = (const float*)d_in[6];
    const float* bk = (const float*)d_in[7];
    const float* Wv = (const float*)d_in[8];
    const float* bv = (const float*)d_in[9];
    const float* Wo = (const float*)d_in[10];
    const float* bo = (const float*)d_in[11];

    const size_t NTC = (size_t)B_ * T_ * C_;  // 4,194,304
    const size_t NW = (size_t)C_ * C_;        // 1,048,576

    char* ws = (char*)d_ws;
    size_t off = 0;
    u16* qb = (u16*)(ws + off);  off += NTC * 2;
    u16* kb = (u16*)(ws + off);  off += NTC * 2;
    u16* vb = (u16*)(ws + off);  off += NTC * 2;
    u16* Wqb = (u16*)(ws + off); off += NW * 2;
    u16* Wkb = (u16*)(ws + off); off += NW * 2;
    u16* Wvb = (u16*)(ws + off); off += NW * 2;
    u16* Wob = (u16*)(ws + off); off += NW * 2;
    u16* Qp = (u16*)(ws + off);  off += NTC * 2;
    u16* Kp = (u16*)(ws + off);  off += NTC * 2;
    u16* Vp = (u16*)(ws + off);  off += NTC * 2;
    u16* AOb = (u16*)(ws + off); off += NTC * 2;

    // after gemm3, qb/kb/vb are dead -> reuse for attention partials
    u16* OP0 = qb;            // unnormalized partial O, z=0 (bf16)
    u16* OP1 = kb;            // unnormalized partial O, z=1 (bf16)
    float* ML = (float*)vb;   // [z][bh][T][2] fp32 (m,l)

    cvt3_kernel<<<dim3(512, 1, 3), 256, 0, stream>>>(q, k, v, qb, kb, vb, (int)(NTC / 4));
    cvt4_kernel<<<dim3(128, 1, 4), 256, 0, stream>>>(Wq, Wk, Wv, Wo, Wqb, Wkb, Wvb, Wob, (int)(NW / 4));

    const int M = B_ * T_;  // 4096
    dim3 g3(C_ / 64, M / 128, 3);  // (16, 32, 3) = 1536 blocks
    gemm3_kernel<<<g3, 256, 0, stream>>>(qb, kb, vb, Wqb, Wkb, Wvb, bq, bk, bv,
                                         Qp, Kp, Vp, M, C_, C_);

    attn_kernel<<<1024, 256, 0, stream>>>(Qp, Kp, Vp, OP0, OP1, ML);

    merge_kernel<<<(int)(NTC / 8 / 256), 256, 0, stream>>>(OP0, OP1, ML, AOb);

    dim3 g1(C_ / 64, M / 128, 1);
    gemm_f32_kernel<<<g1, 256, 0, stream>>>(AOb, Wob, bo, (float*)d_out, M, C_, C_);
}